// Round 13
// baseline (193.777 us; speedup 1.0000x reference)
//
#include <hip/hip_runtime.h>
#include <hip/hip_bf16.h>

// ---------------------------------------------------------------------------
// Sub_Cluster_Level_GCN — round 12:
//   * k_sum: LDS rowlist prefetch + 8-row unroll, PLAIN cached loads/stores
//     (nontemporal removed — caused post-timing divergence via poison/L2
//      interaction under graph replay; G16 non-coherent XCD L2s)
//   4 kernels + 1 memset total.
// ---------------------------------------------------------------------------

#define NROW 50000
#define DIM  2048
#define NSUB 2000
#define BB   256
#define KK   64
#define NHID 512
#define DOUT 256
#define MM   (BB * KK)
#define MU   2304
#define CAP  128

typedef __attribute__((ext_vector_type(8))) short bf16x8;
typedef __attribute__((ext_vector_type(4))) float f32x4;

__device__ __forceinline__ unsigned short f2bf(float f) {
  union { float f; unsigned u; } v; v.f = f;
  unsigned r = v.u + 0x7FFF + ((v.u >> 16) & 1);
  return (unsigned short)(r >> 16);
}
__device__ __forceinline__ float bf2f(unsigned short h) {
  union { unsigned u; float f; } v; v.u = ((unsigned)h) << 16;
  return v.f;
}

// ---- build (196 blocks) + W transposes (2368) + r0 cast (304) --------------
__global__ __launch_bounds__(256) void k_build_misc(const int* __restrict__ sub_label,
                                                    int* __restrict__ cnt,
                                                    int* __restrict__ rowlist,
                                                    const float* __restrict__ W1,
                                                    const float* __restrict__ W2,
                                                    const float* __restrict__ Wc1,
                                                    unsigned short* __restrict__ W1t,
                                                    unsigned short* __restrict__ W2t,
                                                    unsigned short* __restrict__ Wc1t,
                                                    const int* __restrict__ indexes,
                                                    const float* __restrict__ features,
                                                    unsigned short* __restrict__ u_bf,
                                                    float* __restrict__ norms0) {
  int bid = blockIdx.x;
  int t = threadIdx.x;
  if (bid < 196) {
    int i = bid * 256 + t;
    if (i < NROW) {
      int s = sub_label[i];
      int pos = atomicAdd(&cnt[s], 1);
      rowlist[(s << 7) + pos] = i;
    }
    return;
  }
  bid -= 196;
  if (bid >= 2368) {
    int row = bid - 2368;              // 0..303
    unsigned short* dst = u_bf + (size_t)(NSUB + row) * DIM + t * 8;
    if (row >= BB) {
      bf16x8 z = {0, 0, 0, 0, 0, 0, 0, 0};
      *(bf16x8*)dst = z;
      return;
    }
    const float* src = features + (size_t)indexes[row] * DIM + t * 8;
    float4 v0 = *(const float4*)(src);
    float4 v1 = *(const float4*)(src + 4);
    float ss = v0.x * v0.x + v0.y * v0.y + v0.z * v0.z + v0.w * v0.w +
               v1.x * v1.x + v1.y * v1.y + v1.z * v1.z + v1.w * v1.w;
    __shared__ float red[256];
    red[t] = ss;
    __syncthreads();
    for (int s2 = 128; s2 > 0; s2 >>= 1) {
      if (t < s2) red[t] += red[t + s2];
      __syncthreads();
    }
    float nrm = sqrtf(red[0]);
    if (t == 0) norms0[row] = nrm;
    float scale = 1.0f / nrm;
    bf16x8 o;
    o[0] = (short)f2bf(v0.x * scale); o[1] = (short)f2bf(v0.y * scale);
    o[2] = (short)f2bf(v0.z * scale); o[3] = (short)f2bf(v0.w * scale);
    o[4] = (short)f2bf(v1.x * scale); o[5] = (short)f2bf(v1.y * scale);
    o[6] = (short)f2bf(v1.z * scale); o[7] = (short)f2bf(v1.w * scale);
    *(bf16x8*)dst = o;
    return;
  }
  const float* src;
  unsigned short* dst;
  int Nsrc, Kdst, ntn, local;
  if (bid < 1024)      { local = bid;        src = W1;                        dst = W1t;                      Nsrc = NHID; Kdst = DIM;  ntn = 16; }
  else if (bid < 2048) { local = bid - 1024; src = W1 + (size_t)DIM * NHID;   dst = W1t + (size_t)NHID * DIM; Nsrc = NHID; Kdst = DIM;  ntn = 16; }
  else if (bid < 2176) { local = bid - 2048; src = W2;                        dst = W2t;                      Nsrc = DOUT; Kdst = NHID; ntn = 8; }
  else if (bid < 2304) { local = bid - 2176; src = W2 + (size_t)NHID * DOUT;  dst = W2t + (size_t)DOUT * NHID;Nsrc = DOUT; Kdst = NHID; ntn = 8; }
  else                 { local = bid - 2304; src = Wc1;                       dst = Wc1t;                     Nsrc = DOUT; Kdst = DOUT; ntn = 8; }
  int n0 = (local % ntn) * 32, k0 = (local / ntn) * 32;
  __shared__ float tile[32][33];
  int c = t & 31, r8 = t >> 5;
#pragma unroll
  for (int i = 0; i < 4; i++) {
    int r = r8 + i * 8;
    tile[r][c] = src[(size_t)(k0 + r) * Nsrc + n0 + c];
  }
  __syncthreads();
#pragma unroll
  for (int i = 0; i < 4; i++) {
    int r = r8 + i * 8;
    dst[(size_t)(n0 + r) * Kdst + k0 + c] = f2bf(tile[c][r]);
  }
}

// ------- streaming cluster sum: mean + simm + nums + u row ------------------
__global__ __launch_bounds__(256) void k_sum(const float* __restrict__ features,
                                             const int* __restrict__ rowlist,
                                             const int* __restrict__ cnt,
                                             float* __restrict__ submean,
                                             float* __restrict__ simm,
                                             float* __restrict__ nums,
                                             unsigned short* __restrict__ u_bf) {
  int s = blockIdx.x;
  int t = threadIdx.x;
  int n = cnt[s];
  __shared__ int rls[CAP];
  if (t < CAP) rls[t] = rowlist[(s << 7) + t];
  __syncthreads();

  float acc[8] = {0, 0, 0, 0, 0, 0, 0, 0};
  int r = 0;
  for (; r + 7 < n; r += 8) {
    float4 v[16];
#pragma unroll
    for (int i = 0; i < 8; i++) {
      const float* row = features + (size_t)rls[r + i] * DIM + t * 8;
      v[2 * i]     = *(const float4*)(row);
      v[2 * i + 1] = *(const float4*)(row + 4);
    }
#pragma unroll
    for (int i = 0; i < 8; i++) {
      acc[0] += v[2 * i].x;     acc[1] += v[2 * i].y;
      acc[2] += v[2 * i].z;     acc[3] += v[2 * i].w;
      acc[4] += v[2 * i + 1].x; acc[5] += v[2 * i + 1].y;
      acc[6] += v[2 * i + 1].z; acc[7] += v[2 * i + 1].w;
    }
  }
  for (; r < n; r++) {
    const float* row = features + (size_t)rls[r] * DIM + t * 8;
    float4 v0 = *(const float4*)(row);
    float4 v1 = *(const float4*)(row + 4);
    acc[0] += v0.x; acc[1] += v0.y; acc[2] += v0.z; acc[3] += v0.w;
    acc[4] += v1.x; acc[5] += v1.y; acc[6] += v1.z; acc[7] += v1.w;
  }
  float inv = 1.0f / (float)(n > 0 ? n : 1);
  float m[8];
  float ss = 0.f;
#pragma unroll
  for (int i = 0; i < 8; i++) { m[i] = acc[i] * inv; ss += m[i] * m[i]; }
  float* outp = submean + (size_t)s * DIM + t * 8;
  *(float4*)(outp)     = make_float4(m[0], m[1], m[2], m[3]);
  *(float4*)(outp + 4) = make_float4(m[4], m[5], m[6], m[7]);
  __shared__ float red[256];
  red[t] = ss;
  __syncthreads();
  for (int s2 = 128; s2 > 0; s2 >>= 1) {
    if (t < s2) red[t] += red[t + s2];
    __syncthreads();
  }
  float tot = red[0];
  if (t == 0) {
    simm[s] = tot;
    nums[s] = (float)n;
  }
  float scale = (tot > 0.f) ? (1.0f / sqrtf(tot)) : 0.f;
  bf16x8 o;
  o[0] = (short)f2bf(m[0] * scale); o[1] = (short)f2bf(m[1] * scale);
  o[2] = (short)f2bf(m[2] * scale); o[3] = (short)f2bf(m[3] * scale);
  o[4] = (short)f2bf(m[4] * scale); o[5] = (short)f2bf(m[5] * scale);
  o[6] = (short)f2bf(m[6] * scale); o[7] = (short)f2bf(m[7] * scale);
  *(bf16x8*)(u_bf + (size_t)s * DIM + t * 8) = o;
}

// ------- fused gram (256 blocks) + gemm1 (144 tiles), 512 threads -----------
#define NGEMM 144
__global__ __launch_bounds__(512) void k_gram_gemm(const unsigned short* __restrict__ u_bf,
                                                   const unsigned short* __restrict__ W1tp,
                                                   unsigned short* __restrict__ UR1,
                                                   const int* __restrict__ sub_label,
                                                   const int* __restrict__ knn,
                                                   const float* __restrict__ simm,
                                                   const float* __restrict__ norms0,
                                                   const float* __restrict__ all_pred,
                                                   float* __restrict__ A,
                                                   int* __restrict__ sublabs) {
  __shared__ char big[32768];
  __shared__ int slr[64];
  __shared__ float nks[64], wjs[64];
  const int t = threadIdx.x;
  const int w = t >> 6, lane = t & 63;
  const int lr = lane & 15, kg = lane >> 4;

  if (blockIdx.x < NGEMM) {
    constexpr int KTOT = DIM;
    constexpr int NTOT = 2 * NHID;
    unsigned short* As = (unsigned short*)big;
    unsigned short* Bs = (unsigned short*)(big + 16384);
    int orig = blockIdx.x;
    int swz = (orig & 7) * (NGEMM / 8) + (orig >> 3);
    const int nt = (swz & 7) * 128;
    const int mt = (swz >> 3) * 128;
    const int wr = w >> 2, wc = w & 3;

    f32x4 acc[4][2];
#pragma unroll
    for (int m = 0; m < 4; m++)
#pragma unroll
      for (int n = 0; n < 2; n++) acc[m][n] = (f32x4){0.f, 0.f, 0.f, 0.f};

    for (int kc = 0; kc < KTOT / 64; kc++) {
      const int k0 = kc * 64;
#pragma unroll
      for (int i = 0; i < 2; i++) {
        int q = (w * 2 + i) * 64 + lane;
        int r = q >> 3;
        int cl = (q & 7) ^ (r & 7);
        __builtin_amdgcn_global_load_lds(
            (const __attribute__((address_space(1))) void*)(u_bf + (size_t)(mt + r) * KTOT + k0 + cl * 8),
            (__attribute__((address_space(3))) void*)(As + (w * 2 + i) * 512), 16, 0, 0);
      }
#pragma unroll
      for (int i = 0; i < 2; i++) {
        int q = (w * 2 + i) * 64 + lane;
        int r = q >> 3;
        int cl = (q & 7) ^ (r & 7);
        __builtin_amdgcn_global_load_lds(
            (const __attribute__((address_space(1))) void*)(W1tp + (size_t)(nt + r) * KTOT + k0 + cl * 8),
            (__attribute__((address_space(3))) void*)(Bs + (w * 2 + i) * 512), 16, 0, 0);
      }
      __syncthreads();
#pragma unroll
      for (int ks = 0; ks < 2; ks++) {
        bf16x8 af[4], bfr[2];
        const int ch = ks * 4 + kg;
#pragma unroll
        for (int m = 0; m < 4; m++) {
          int row = wr * 64 + m * 16 + lr;
          af[m] = *(const bf16x8*)&As[row * 64 + ((ch ^ (row & 7)) << 3)];
        }
#pragma unroll
        for (int n = 0; n < 2; n++) {
          int row = wc * 32 + n * 16 + lr;
          bfr[n] = *(const bf16x8*)&Bs[row * 64 + ((ch ^ (row & 7)) << 3)];
        }
#pragma unroll
        for (int m = 0; m < 4; m++)
#pragma unroll
          for (int n = 0; n < 2; n++)
            acc[m][n] = __builtin_amdgcn_mfma_f32_16x16x32_bf16(af[m], bfr[n], acc[m][n], 0, 0, 0);
      }
      __syncthreads();
    }
#pragma unroll
    for (int m = 0; m < 4; m++) {
      int rm = mt + wr * 64 + m * 16 + kg * 4;
#pragma unroll
      for (int n = 0; n < 2; n++) {
        int col = nt + wc * 32 + n * 16 + lr;
#pragma unroll
        for (int j = 0; j < 4; j++)
          UR1[(size_t)(rm + j) * NTOT + col] = f2bf(acc[m][n][j]);
      }
    }
    return;
  }

  int b = blockIdx.x - NGEMM;
  unsigned short* Xs = (unsigned short*)big;
  if (t < 64) {
    int sl = sub_label[knn[b * KK + t]];
    sublabs[b * KK + t] = sl;
    slr[t] = (t == 0) ? (NSUB + b) : sl;
    float s2 = (t == 0) ? 0.f : simm[sl];
    nks[t] = (t == 0) ? norms0[b] : ((s2 > 0.f) ? sqrtf(s2) : 0.f);
    wjs[t] = expf(all_pred[(size_t)(b * KK + t) * 2 + 1]);
  }
  __syncthreads();

  const int rb = w & 3;
  const int cp = w >> 2;
  int rloc[4], clsw[4];
#pragma unroll
  for (int i = 0; i < 4; i++) {
    rloc[i] = w * 8 + i * 2 + (lane >> 5);
    clsw[i] = (lane & 31) ^ (rloc[i] & 7);
  }

  f32x4 acc0 = {0.f, 0.f, 0.f, 0.f}, acc1 = {0.f, 0.f, 0.f, 0.f};
  for (int c = 0; c < 8; c++) {
    if (c) __syncthreads();
#pragma unroll
    for (int i = 0; i < 4; i++) {
      const unsigned short* src =
          u_bf + (size_t)slr[rloc[i]] * DIM + c * 256 + clsw[i] * 8;
      __builtin_amdgcn_global_load_lds(
          (const __attribute__((address_space(1))) void*)src,
          (__attribute__((address_space(3))) void*)(Xs + (w * 8 + i * 2) * 256), 16, 0, 0);
    }
    __syncthreads();
#pragma unroll
    for (int ks = 0; ks < 8; ks++) {
      const int ch = ks * 4 + kg;
      int Ra = rb * 16 + lr;
      bf16x8 fa = *(const bf16x8*)&Xs[Ra * 256 + ((ch ^ (Ra & 7)) << 3)];
      int R0 = (cp * 2) * 16 + lr;
      bf16x8 f0 = *(const bf16x8*)&Xs[R0 * 256 + ((ch ^ (R0 & 7)) << 3)];
      int R1 = (cp * 2 + 1) * 16 + lr;
      bf16x8 f1 = *(const bf16x8*)&Xs[R1 * 256 + ((ch ^ (R1 & 7)) << 3)];
      acc0 = __builtin_amdgcn_mfma_f32_16x16x32_bf16(fa, f0, acc0, 0, 0, 0);
      acc1 = __builtin_amdgcn_mfma_f32_16x16x32_bf16(fa, f1, acc1, 0, 0, 0);
    }
  }

  __syncthreads();
  float* Cs = (float*)big;
#pragma unroll
  for (int r = 0; r < 4; r++) {
    Cs[(rb * 16 + kg * 4 + r) * 68 + cp * 32 + lr] = acc0[r];
    Cs[(rb * 16 + kg * 4 + r) * 68 + cp * 32 + 16 + lr] = acc1[r];
  }
  __syncthreads();

  int row = t >> 3, seg = t & 7;
  float nr = nks[row];
  float v[8];
  float mx = -1e30f;
#pragma unroll
  for (int i = 0; i < 8; i++) {
    int j = seg * 8 + i;
    v[i] = Cs[row * 68 + j] * nr * nks[j] * wjs[j];
    mx = fmaxf(mx, v[i]);
  }
  mx = fmaxf(mx, __shfl_xor(mx, 1));
  mx = fmaxf(mx, __shfl_xor(mx, 2));
  mx = fmaxf(mx, __shfl_xor(mx, 4));
  float sum = 0.f;
#pragma unroll
  for (int i = 0; i < 8; i++) {
    v[i] = expf(v[i] - mx);
    sum += v[i];
  }
  sum += __shfl_xor(sum, 1);
  sum += __shfl_xor(sum, 2);
  sum += __shfl_xor(sum, 4);
  float inv = 1.0f / sum;
  float* outp = A + ((size_t)b * KK + row) * KK + seg * 8;
  *(float4*)(outp)     = make_float4(v[0] * inv, v[1] * inv, v[2] * inv, v[3] * inv);
  *(float4*)(outp + 4) = make_float4(v[4] * inv, v[5] * inv, v[6] * inv, v[7] * inv);
}

// ---- l12c: combine1 + gemm2 + combine2 + classifier, all per-sample --------
__global__ __launch_bounds__(512) void k_l12c(const float* __restrict__ A,
                                              const unsigned short* __restrict__ UR1,
                                              const int* __restrict__ sublabs,
                                              const float* __restrict__ b1,
                                              const unsigned short* __restrict__ W2tp,
                                              const float* __restrict__ b2,
                                              const unsigned short* __restrict__ Wc1t,
                                              const float* __restrict__ bc1,
                                              const float* __restrict__ pa,
                                              const float* __restrict__ Wc2,
                                              const float* __restrict__ bc2,
                                              float* __restrict__ probs) {
  __shared__ char lds[131072];
  unsigned short* x1s = (unsigned short*)lds;              // [64][512] 64KB
  char* R = lds + 65536;
  unsigned short* Pl = (unsigned short*)R;                 // [64][80]
  unsigned short* Bl = (unsigned short*)(R + 10240);       // [128][80]
  unsigned short* Ag = (unsigned short*)(R + 30720);       // [64][136]
  float* Raf = (float*)(R + 48128);                        // [128]
  float* red8 = (float*)(R + 48640);                       // [64][8]
  int* slh = (int*)(R + 50688);                            // [64]
  unsigned short* Ws = (unsigned short*)R;                 // stage A: [512][64] 64KB
  unsigned short* Za = (unsigned short*)lds;               // stage B: [64][264]
  unsigned short* Zb = (unsigned short*)(lds + 34816);     // [256][72]
  unsigned short* Pl2 = (unsigned short*)(lds + 71680);    // [64][72]
  unsigned short* x2s = (unsigned short*)(lds + 34816);    // stage C: [64][256]
  unsigned short* Ws2 = (unsigned short*)lds;              // stage C: [256][64]
  float* Lred = (float*)(lds + 71680);                     // [64][8][2]

  const int b = blockIdx.x;
  const int t = threadIdx.x;
  const int w = t >> 6, lane = t & 63;
  const int lr = lane & 15, kg = lane >> 4;
  constexpr int NSTR = 2 * NHID;

  if (t < 64) slh[t] = sublabs[b * KK + t];
  {
    int pk = t & 63, pp = t >> 6;
    const float* Arow = A + ((size_t)b * KK + pk) * KK;
    float part = 0.f;
#pragma unroll
    for (int e = 0; e < 8; e++) {
      int j = pp * 8 + e;
      float av = Arow[j];
      if (j > 0) {
        Pl[pk * 80 + j] = f2bf(av);
        part += av;
      }
    }
    red8[pk * 8 + pp] = part;
  }
  __syncthreads();
  if (t < 64) {
    float rs = 0.f;
#pragma unroll
    for (int p = 0; p < 8; p++) rs += red8[t * 8 + p];
    Pl[t * 80 + 0] = f2bf(-rs);
  }

  for (int db = 0; db < 4; db++) {
    const int dblk = db * 128;
    __syncthreads();
    {
      int gj = t >> 3, gc0 = t & 7;
      size_t brow = (gj == 0) ? (size_t)(NSUB + b) : (size_t)slh[gj];
      const unsigned short* Bp = UR1 + brow * NSTR + NHID + dblk;
#pragma unroll
      for (int it = 0; it < 2; it++) {
        int c = gc0 + it * 8;
        bf16x8 v = *(const bf16x8*)(Bp + c * 8);
#pragma unroll
        for (int e = 0; e < 8; e++) Bl[(c * 8 + e) * 80 + gj] = v[e];
      }
    }
    {
      int ak = t >> 3, ac0 = t & 7;
      const unsigned short* Ap = UR1 + (size_t)slh[ak] * NSTR + dblk;
#pragma unroll
      for (int it = 0; it < 2; it++) {
        int c = ac0 + it * 8;
        *(bf16x8*)&Ag[ak * 136 + c * 8] = *(const bf16x8*)(Ap + c * 8);
      }
      if (t < 128) Raf[t] = bf2f(UR1[(size_t)(NSUB + b) * NSTR + dblk + t]);
    }
    __syncthreads();

    f32x4 acc[4];
#pragma unroll
    for (int m = 0; m < 4; m++) acc[m] = (f32x4){0.f, 0.f, 0.f, 0.f};
#pragma unroll
    for (int ks = 0; ks < 2; ks++) {
      const int ch = ks * 4 + kg;
      bf16x8 bfr = *(const bf16x8*)&Bl[(w * 16 + lr) * 80 + ch * 8];
#pragma unroll
      for (int m = 0; m < 4; m++) {
        bf16x8 af = *(const bf16x8*)&Pl[(m * 16 + lr) * 80 + ch * 8];
        acc[m] = __builtin_amdgcn_mfma_f32_16x16x32_bf16(af, bfr, acc[m], 0, 0, 0);
      }
    }
#pragma unroll
    for (int m = 0; m < 4; m++) {
      int d = w * 16 + lr;
      float bd = b1[dblk + d];
#pragma unroll
      for (int j = 0; j < 4; j++) {
        int k = m * 16 + kg * 4 + j;
        float v = acc[m][j] + bd;
        if (k > 0) v += bf2f(Ag[k * 136 + d]) - Raf[d];
        int cg = dblk + d;
        int C = cg >> 3;
        x1s[k * 512 + (((C ^ (k & 7)) << 3) | (cg & 7))] = f2bf(fmaxf(v, 0.f));
      }
    }
  }
  __syncthreads();

  const int wr = w >> 2, wc = w & 3;
  f32x4 accA[2][8];
#pragma unroll
  for (int m = 0; m < 2; m++)
#pragma unroll
    for (int n = 0; n < 8; n++) accA[m][n] = (f32x4){0.f, 0.f, 0.f, 0.f};

  for (int kc = 0; kc < 8; kc++) {
    const int k0 = kc * 64;
    if (kc) __syncthreads();
#pragma unroll
    for (int i = 0; i < 8; i++) {
      int r = w * 64 + i * 8 + (lane >> 3);
      int cl = (lane & 7) ^ (r & 7);
      __builtin_amdgcn_global_load_lds(
          (const __attribute__((address_space(1))) void*)(W2tp + (size_t)r * NHID + k0 + cl * 8),
          (__attribute__((address_space(3))) void*)(Ws + (w * 64 + i * 8) * 64), 16, 0, 0);
    }
    __syncthreads();
#pragma unroll
    for (int ks = 0; ks < 2; ks++) {
      const int ch = ks * 4 + kg;
      const int C = kc * 8 + ch;
      bf16x8 af[2], bfr[8];
#pragma unroll
      for (int m = 0; m < 2; m++) {
        int row = wr * 32 + m * 16 + lr;
        af[m] = *(const bf16x8*)&x1s[row * 512 + ((C ^ (row & 7)) << 3)];
      }
#pragma unroll
      for (int n = 0; n < 8; n++) {
        int row = wc * 128 + n * 16 + lr;
        bfr[n] = *(const bf16x8*)&Ws[row * 64 + ((ch ^ (row & 7)) << 3)];
      }
#pragma unroll
      for (int m = 0; m < 2; m++)
#pragma unroll
        for (int n = 0; n < 8; n++)
          accA[m][n] = __builtin_amdgcn_mfma_f32_16x16x32_bf16(af[m], bfr[n], accA[m][n], 0, 0, 0);
    }
  }
  __syncthreads();

#pragma unroll
  for (int m = 0; m < 2; m++) {
#pragma unroll
    for (int n = 0; n < 8; n++) {
      int col = wc * 128 + n * 16 + lr;
#pragma unroll
      for (int j = 0; j < 4; j++) {
        int row = wr * 32 + m * 16 + kg * 4 + j;
        unsigned short hv = f2bf(accA[m][n][j]);
        if (col < 256) Za[row * 264 + col] = hv;
        else           Zb[(col - 256) * 72 + row] = hv;
      }
    }
  }
  {
    const float* Ap = A + (size_t)b * KK * KK + t * 8;
    float4 f0 = *(const float4*)(Ap);
    float4 f1 = *(const float4*)(Ap + 4);
    bf16x8 hv;
    hv[0] = (short)f2bf(f0.x); hv[1] = (short)f2bf(f0.y);
    hv[2] = (short)f2bf(f0.z); hv[3] = (short)f2bf(f0.w);
    hv[4] = (short)f2bf(f1.x); hv[5] = (short)f2bf(f1.y);
    hv[6] = (short)f2bf(f1.z); hv[7] = (short)f2bf(f1.w);
    *(bf16x8*)&Pl2[(t >> 3) * 72 + (t & 7) * 8] = hv;
  }
  __syncthreads();

  f32x4 acc2[4][2];
#pragma unroll
  for (int m = 0; m < 4; m++)
#pragma unroll
    for (int n = 0; n < 2; n++) acc2[m][n] = (f32x4){0.f, 0.f, 0.f, 0.f};
#pragma unroll
  for (int ks = 0; ks < 2; ks++) {
    const int ch = ks * 4 + kg;
    bf16x8 af[4], bfr[2];
#pragma unroll
    for (int m = 0; m < 4; m++) af[m] = *(const bf16x8*)&Pl2[(m * 16 + lr) * 72 + ch * 8];
#pragma unroll
    for (int n = 0; n < 2; n++) bfr[n] = *(const bf16x8*)&Zb[(w * 32 + n * 16 + lr) * 72 + ch * 8];
#pragma unroll
    for (int m = 0; m < 4; m++)
#pragma unroll
      for (int n = 0; n < 2; n++)
        acc2[m][n] = __builtin_amdgcn_mfma_f32_16x16x32_bf16(af[m], bfr[n], acc2[m][n], 0, 0, 0);
  }
  __syncthreads();

#pragma unroll
  for (int m = 0; m < 4; m++) {
#pragma unroll
    for (int n = 0; n < 2; n++) {
      int d = w * 32 + n * 16 + lr;
      float bd = b2[d];
#pragma unroll
      for (int j = 0; j < 4; j++) {
        int k = m * 16 + kg * 4 + j;
        float v = acc2[m][n][j] + bf2f(Za[k * 264 + d]) + bd;
        int C = d >> 3;
        x2s[k * 256 + (((C ^ (k & 7)) << 3) | (d & 7))] = f2bf(fmaxf(v, 0.f));
      }
    }
  }
  __syncthreads();

  f32x4 acc3[4][2];
#pragma unroll
  for (int m = 0; m < 4; m++)
#pragma unroll
    for (int n = 0; n < 2; n++) acc3[m][n] = (f32x4){0.f, 0.f, 0.f, 0.f};

  for (int kc = 0; kc < 4; kc++) {
    const int k0 = kc * 64;
    if (kc) __syncthreads();
#pragma unroll
    for (int i = 0; i < 4; i++) {
      int r = w * 32 + i * 8 + (lane >> 3);
      int cl = (lane & 7) ^ (r & 7);
      __builtin_amdgcn_global_load_lds(
          (const __attribute__((address_space(1))) void*)(Wc1t + (size_t)r * DOUT + k0 + cl * 8),
          (__attribute__((address_space(3))) void*)(Ws2 + (w * 32 + i * 8) * 64), 16, 0, 0);
    }
    __syncthreads();
#pragma unroll
    for (int ks = 0; ks < 2; ks++) {
      const int ch = ks * 4 + kg;
      const int C = kc * 8 + ch;
      bf16x8 af[4], bfr[2];
#pragma unroll
      for (int m = 0; m < 4; m++) {
        int row = m * 16 + lr;
        af[m] = *(const bf16x8*)&x2s[row * 256 + ((C ^ (row & 7)) << 3)];
      }
#pragma unroll
      for (int n = 0; n < 2; n++) {
        int row = w * 32 + n * 16 + lr;
        bfr[n] = *(const bf16x8*)&Ws2[row * 64 + ((ch ^ (row & 7)) << 3)];
      }
#pragma unroll
      for (int m = 0; m < 4; m++)
#pragma unroll
        for (int n = 0; n < 2; n++)
          acc3[m][n] = __builtin_amdgcn_mfma_f32_16x16x32_bf16(af[m], bfr[n], acc3[m][n], 0, 0, 0);
    }
  }

  float bc1v[2], pav[2], w0v[2], w1v[2];
#pragma unroll
  for (int n = 0; n < 2; n++) {
    int col = w * 32 + n * 16 + lr;
    bc1v[n] = bc1[col];
    pav[n] = pa[col];
    w0v[n] = Wc2[col * 2 + 0];
    w1v[n] = Wc2[col * 2 + 1];
  }
  __syncthreads();
#pragma unroll
  for (int m = 0; m < 4; m++) {
#pragma unroll
    for (int j = 0; j < 4; j++) {
      float p0 = 0.f, p1 = 0.f;
#pragma unroll
      for (int n = 0; n < 2; n++) {
        float h = acc3[m][n][j] + bc1v[n];
        h = (h >= 0.f) ? h : pav[n] * h;
        p0 += h * w0v[n];
        p1 += h * w1v[n];
      }
      p0 += __shfl_xor(p0, 1); p1 += __shfl_xor(p1, 1);
      p0 += __shfl_xor(p0, 2); p1 += __shfl_xor(p1, 2);
      p0 += __shfl_xor(p0, 4); p1 += __shfl_xor(p1, 4);
      p0 += __shfl_xor(p0, 8); p1 += __shfl_xor(p1, 8);
      if (lr == 0) {
        int rowl = m * 16 + kg * 4 + j;
        Lred[(rowl * 8 + w) * 2 + 0] = p0;
        Lred[(rowl * 8 + w) * 2 + 1] = p1;
      }
    }
  }
  __syncthreads();
  if (t < 64) {
    float l0 = bc2[0], l1 = bc2[1];
#pragma unroll
    for (int p = 0; p < 8; p++) {
      l0 += Lred[(t * 8 + p) * 2 + 0];
      l1 += Lred[(t * 8 + p) * 2 + 1];
    }
    float m = fmaxf(l0, l1);
    float e0 = expf(l0 - m), e1 = expf(l1 - m);
    float inv = 1.0f / (e0 + e1);
    *(float2*)(probs + (size_t)(b * KK + t) * 2) = make_float2(e0 * inv, e1 * inv);
  }
}

// ---------------------------------------------------------------------------

extern "C" void kernel_launch(void* const* d_in, const int* in_sizes, int n_in,
                              void* d_out, int out_size, void* d_ws, size_t ws_size,
                              hipStream_t stream) {
  const int* indexes = (const int*)d_in[0];
  const float* features = (const float*)d_in[1];
  const int* sub_label = (const int*)d_in[3];
  const int* knn = (const int*)d_in[6];
  const float* all_pred = (const float*)d_in[7];
  const float* W1 = (const float*)d_in[9];
  const float* b1 = (const float*)d_in[10];
  const float* W2 = (const float*)d_in[11];
  const float* b2 = (const float*)d_in[12];
  const float* Wc1 = (const float*)d_in[13];
  const float* bc1 = (const float*)d_in[14];
  const float* pa = (const float*)d_in[15];
  const float* Wc2 = (const float*)d_in[16];
  const float* bc2 = (const float*)d_in[17];

  float* out = (float*)d_out;
  float* probs = out;
  float* simm = out + 32768;
  float* submean = out + 34768;
  float* nums = out + 4130768;

  char* ws = (char*)d_ws;
  size_t off = 0;
  unsigned short* u_bf = (unsigned short*)(ws + off); off += (size_t)MU * DIM * 2;
  unsigned short* UR1  = (unsigned short*)(ws + off); off += (size_t)MU * 2 * NHID * 2;
  unsigned short* W1tp = (unsigned short*)(ws + off); off += (size_t)(2 * NHID) * DIM * 2;
  unsigned short* W2tp = (unsigned short*)(ws + off); off += (size_t)(2 * DOUT) * NHID * 2;
  unsigned short* Wc1t = (unsigned short*)(ws + off); off += (size_t)DOUT * DOUT * 2;
  float* Abuf = (float*)(ws + off); off += (size_t)MM * KK * 4;
  int* cnt     = (int*)(ws + off); off += NSUB * 4;
  int* rowlist = (int*)(ws + off); off += (size_t)NSUB * CAP * 4;
  int* sublabs = (int*)(ws + off); off += (size_t)MM * 4;
  float* norms0 = (float*)(ws + off); off += (size_t)BB * 4;

  (void)hipMemsetAsync(cnt, 0, NSUB * sizeof(int), stream);

  k_build_misc<<<196 + 2368 + 304, 256, 0, stream>>>(
      sub_label, cnt, rowlist, W1, W2, Wc1, W1tp, W2tp, Wc1t,
      indexes, features, u_bf, norms0);
  k_sum<<<NSUB, 256, 0, stream>>>(features, rowlist, cnt,
                                  submean, simm, nums, u_bf);
  k_gram_gemm<<<NGEMM + BB, 512, 0, stream>>>(u_bf, W1tp, UR1, sub_label, knn,
                                              simm, norms0, all_pred, Abuf, sublabs);
  k_l12c<<<BB, 512, 0, stream>>>(Abuf, UR1, sublabs, b1, W2tp, b2,
                                 Wc1t, bc1, pa, Wc2, bc2, probs);
}

// Round 14
// 185.350 us; speedup vs baseline: 1.0455x; 1.0455x over previous
//
#include <hip/hip_runtime.h>
#include <hip/hip_bf16.h>

// ---------------------------------------------------------------------------
// Sub_Cluster_Level_GCN — round 13:
//   * revert to round-9 launch structure (tiny build -> fused sum+misc)
//     so misc W-transpose traffic overlaps the sum tail again
//   * keep LDS rowlist prefetch (from r10), 4-row unroll, NO nontemporal
//   4 kernels + 1 memset total.
// ---------------------------------------------------------------------------

#define NROW 50000
#define DIM  2048
#define NSUB 2000
#define BB   256
#define KK   64
#define NHID 512
#define DOUT 256
#define MM   (BB * KK)
#define MU   2304
#define CAP  128

typedef __attribute__((ext_vector_type(8))) short bf16x8;
typedef __attribute__((ext_vector_type(4))) float f32x4;

__device__ __forceinline__ unsigned short f2bf(float f) {
  union { float f; unsigned u; } v; v.f = f;
  unsigned r = v.u + 0x7FFF + ((v.u >> 16) & 1);
  return (unsigned short)(r >> 16);
}
__device__ __forceinline__ float bf2f(unsigned short h) {
  union { unsigned u; float f; } v; v.u = ((unsigned)h) << 16;
  return v.f;
}

// ---------------- build: bucketed rowlist ----------------------------------
__global__ __launch_bounds__(256) void k_build(const int* __restrict__ sub_label,
                                               int* __restrict__ cnt,
                                               int* __restrict__ rowlist) {
  int i = blockIdx.x * 256 + threadIdx.x;
  if (i < NROW) {
    int s = sub_label[i];
    int pos = atomicAdd(&cnt[s], 1);
    rowlist[(s << 7) + pos] = i;
  }
}

// --- cluster_sum (2000) + W transposes (2368) + r0 cast (304) in one launch -
__global__ __launch_bounds__(256) void k_sum_misc(const float* __restrict__ features,
                                                  const int* __restrict__ rowlist,
                                                  const int* __restrict__ cnt,
                                                  float* __restrict__ submean,
                                                  float* __restrict__ simm,
                                                  float* __restrict__ nums,
                                                  unsigned short* __restrict__ u_bf,
                                                  const float* __restrict__ W1,
                                                  const float* __restrict__ W2,
                                                  const float* __restrict__ Wc1,
                                                  unsigned short* __restrict__ W1t,
                                                  unsigned short* __restrict__ W2t,
                                                  unsigned short* __restrict__ Wc1t,
                                                  const int* __restrict__ indexes,
                                                  float* __restrict__ norms0) {
  int bid = blockIdx.x;
  int t = threadIdx.x;
  if (bid < NSUB) {
    // ---- cluster mean + simm + nums + u row ----
    int s = bid;
    int n = cnt[s];
    __shared__ int rls[CAP];
    if (t < CAP) rls[t] = rowlist[(s << 7) + t];
    __syncthreads();
    float acc[8] = {0, 0, 0, 0, 0, 0, 0, 0};
    int r = 0;
    for (; r + 3 < n; r += 4) {
      const float* rA = features + (size_t)rls[r] * DIM + t * 8;
      const float* rB = features + (size_t)rls[r + 1] * DIM + t * 8;
      const float* rC = features + (size_t)rls[r + 2] * DIM + t * 8;
      const float* rD = features + (size_t)rls[r + 3] * DIM + t * 8;
      float4 a0 = *(const float4*)(rA), a1 = *(const float4*)(rA + 4);
      float4 b0 = *(const float4*)(rB), b1 = *(const float4*)(rB + 4);
      float4 c0 = *(const float4*)(rC), c1 = *(const float4*)(rC + 4);
      float4 d0 = *(const float4*)(rD), d1 = *(const float4*)(rD + 4);
      acc[0] += (a0.x + b0.x) + (c0.x + d0.x);
      acc[1] += (a0.y + b0.y) + (c0.y + d0.y);
      acc[2] += (a0.z + b0.z) + (c0.z + d0.z);
      acc[3] += (a0.w + b0.w) + (c0.w + d0.w);
      acc[4] += (a1.x + b1.x) + (c1.x + d1.x);
      acc[5] += (a1.y + b1.y) + (c1.y + d1.y);
      acc[6] += (a1.z + b1.z) + (c1.z + d1.z);
      acc[7] += (a1.w + b1.w) + (c1.w + d1.w);
    }
    for (; r < n; r++) {
      const float* row = features + (size_t)rls[r] * DIM + t * 8;
      float4 v0 = *(const float4*)(row);
      float4 v1 = *(const float4*)(row + 4);
      acc[0] += v0.x; acc[1] += v0.y; acc[2] += v0.z; acc[3] += v0.w;
      acc[4] += v1.x; acc[5] += v1.y; acc[6] += v1.z; acc[7] += v1.w;
    }
    float inv = 1.0f / (float)(n > 0 ? n : 1);
    float m[8];
    float ss = 0.f;
#pragma unroll
    for (int i = 0; i < 8; i++) { m[i] = acc[i] * inv; ss += m[i] * m[i]; }
    float* outp = submean + (size_t)s * DIM + t * 8;
    *(float4*)(outp)     = make_float4(m[0], m[1], m[2], m[3]);
    *(float4*)(outp + 4) = make_float4(m[4], m[5], m[6], m[7]);
    __shared__ float red[256];
    red[t] = ss;
    __syncthreads();
    for (int s2 = 128; s2 > 0; s2 >>= 1) {
      if (t < s2) red[t] += red[t + s2];
      __syncthreads();
    }
    float tot = red[0];
    if (t == 0) {
      simm[s] = tot;
      nums[s] = (float)n;
    }
    float scale = (tot > 0.f) ? (1.0f / sqrtf(tot)) : 0.f;
    bf16x8 o;
    o[0] = (short)f2bf(m[0] * scale); o[1] = (short)f2bf(m[1] * scale);
    o[2] = (short)f2bf(m[2] * scale); o[3] = (short)f2bf(m[3] * scale);
    o[4] = (short)f2bf(m[4] * scale); o[5] = (short)f2bf(m[5] * scale);
    o[6] = (short)f2bf(m[6] * scale); o[7] = (short)f2bf(m[7] * scale);
    *(bf16x8*)(u_bf + (size_t)s * DIM + t * 8) = o;
    return;
  }
  bid -= NSUB;
  if (bid >= 2368) {
    // ---- r0 cast/norm ----
    int row = bid - 2368;
    unsigned short* dst = u_bf + (size_t)(NSUB + row) * DIM + t * 8;
    if (row >= BB) {
      bf16x8 z = {0, 0, 0, 0, 0, 0, 0, 0};
      *(bf16x8*)dst = z;
      return;
    }
    const float* src = features + (size_t)indexes[row] * DIM + t * 8;
    float4 v0 = *(const float4*)(src);
    float4 v1 = *(const float4*)(src + 4);
    float ss = v0.x * v0.x + v0.y * v0.y + v0.z * v0.z + v0.w * v0.w +
               v1.x * v1.x + v1.y * v1.y + v1.z * v1.z + v1.w * v1.w;
    __shared__ float red2[256];
    red2[t] = ss;
    __syncthreads();
    for (int s2 = 128; s2 > 0; s2 >>= 1) {
      if (t < s2) red2[t] += red2[t + s2];
      __syncthreads();
    }
    float nrm = sqrtf(red2[0]);
    if (t == 0) norms0[row] = nrm;
    float scale = 1.0f / nrm;
    bf16x8 o;
    o[0] = (short)f2bf(v0.x * scale); o[1] = (short)f2bf(v0.y * scale);
    o[2] = (short)f2bf(v0.z * scale); o[3] = (short)f2bf(v0.w * scale);
    o[4] = (short)f2bf(v1.x * scale); o[5] = (short)f2bf(v1.y * scale);
    o[6] = (short)f2bf(v1.z * scale); o[7] = (short)f2bf(v1.w * scale);
    *(bf16x8*)dst = o;
    return;
  }
  // ---- W transpose tiles ----
  const float* src;
  unsigned short* dst;
  int Nsrc, Kdst, ntn, local;
  if (bid < 1024)      { local = bid;        src = W1;                        dst = W1t;                      Nsrc = NHID; Kdst = DIM;  ntn = 16; }
  else if (bid < 2048) { local = bid - 1024; src = W1 + (size_t)DIM * NHID;   dst = W1t + (size_t)NHID * DIM; Nsrc = NHID; Kdst = DIM;  ntn = 16; }
  else if (bid < 2176) { local = bid - 2048; src = W2;                        dst = W2t;                      Nsrc = DOUT; Kdst = NHID; ntn = 8; }
  else if (bid < 2304) { local = bid - 2176; src = W2 + (size_t)NHID * DOUT;  dst = W2t + (size_t)DOUT * NHID;Nsrc = DOUT; Kdst = NHID; ntn = 8; }
  else                 { local = bid - 2304; src = Wc1;                       dst = Wc1t;                     Nsrc = DOUT; Kdst = DOUT; ntn = 8; }
  int n0 = (local % ntn) * 32, k0 = (local / ntn) * 32;
  __shared__ float tile[32][33];
  int c = t & 31, r8 = t >> 5;
#pragma unroll
  for (int i = 0; i < 4; i++) {
    int r = r8 + i * 8;
    tile[r][c] = src[(size_t)(k0 + r) * Nsrc + n0 + c];
  }
  __syncthreads();
#pragma unroll
  for (int i = 0; i < 4; i++) {
    int r = r8 + i * 8;
    dst[(size_t)(n0 + r) * Kdst + k0 + c] = f2bf(tile[c][r]);
  }
}

// ------- fused gram (256 blocks) + gemm1 (144 tiles), 512 threads -----------
#define NGEMM 144
__global__ __launch_bounds__(512) void k_gram_gemm(const unsigned short* __restrict__ u_bf,
                                                   const unsigned short* __restrict__ W1tp,
                                                   unsigned short* __restrict__ UR1,
                                                   const int* __restrict__ sub_label,
                                                   const int* __restrict__ knn,
                                                   const float* __restrict__ simm,
                                                   const float* __restrict__ norms0,
                                                   const float* __restrict__ all_pred,
                                                   float* __restrict__ A,
                                                   int* __restrict__ sublabs) {
  __shared__ char big[32768];
  __shared__ int slr[64];
  __shared__ float nks[64], wjs[64];
  const int t = threadIdx.x;
  const int w = t >> 6, lane = t & 63;
  const int lr = lane & 15, kg = lane >> 4;

  if (blockIdx.x < NGEMM) {
    constexpr int KTOT = DIM;
    constexpr int NTOT = 2 * NHID;
    unsigned short* As = (unsigned short*)big;
    unsigned short* Bs = (unsigned short*)(big + 16384);
    int orig = blockIdx.x;
    int swz = (orig & 7) * (NGEMM / 8) + (orig >> 3);
    const int nt = (swz & 7) * 128;
    const int mt = (swz >> 3) * 128;
    const int wr = w >> 2, wc = w & 3;

    f32x4 acc[4][2];
#pragma unroll
    for (int m = 0; m < 4; m++)
#pragma unroll
      for (int n = 0; n < 2; n++) acc[m][n] = (f32x4){0.f, 0.f, 0.f, 0.f};

    for (int kc = 0; kc < KTOT / 64; kc++) {
      const int k0 = kc * 64;
#pragma unroll
      for (int i = 0; i < 2; i++) {
        int q = (w * 2 + i) * 64 + lane;
        int r = q >> 3;
        int cl = (q & 7) ^ (r & 7);
        __builtin_amdgcn_global_load_lds(
            (const __attribute__((address_space(1))) void*)(u_bf + (size_t)(mt + r) * KTOT + k0 + cl * 8),
            (__attribute__((address_space(3))) void*)(As + (w * 2 + i) * 512), 16, 0, 0);
      }
#pragma unroll
      for (int i = 0; i < 2; i++) {
        int q = (w * 2 + i) * 64 + lane;
        int r = q >> 3;
        int cl = (q & 7) ^ (r & 7);
        __builtin_amdgcn_global_load_lds(
            (const __attribute__((address_space(1))) void*)(W1tp + (size_t)(nt + r) * KTOT + k0 + cl * 8),
            (__attribute__((address_space(3))) void*)(Bs + (w * 2 + i) * 512), 16, 0, 0);
      }
      __syncthreads();
#pragma unroll
      for (int ks = 0; ks < 2; ks++) {
        bf16x8 af[4], bfr[2];
        const int ch = ks * 4 + kg;
#pragma unroll
        for (int m = 0; m < 4; m++) {
          int row = wr * 64 + m * 16 + lr;
          af[m] = *(const bf16x8*)&As[row * 64 + ((ch ^ (row & 7)) << 3)];
        }
#pragma unroll
        for (int n = 0; n < 2; n++) {
          int row = wc * 32 + n * 16 + lr;
          bfr[n] = *(const bf16x8*)&Bs[row * 64 + ((ch ^ (row & 7)) << 3)];
        }
#pragma unroll
        for (int m = 0; m < 4; m++)
#pragma unroll
          for (int n = 0; n < 2; n++)
            acc[m][n] = __builtin_amdgcn_mfma_f32_16x16x32_bf16(af[m], bfr[n], acc[m][n], 0, 0, 0);
      }
      __syncthreads();
    }
#pragma unroll
    for (int m = 0; m < 4; m++) {
      int rm = mt + wr * 64 + m * 16 + kg * 4;
#pragma unroll
      for (int n = 0; n < 2; n++) {
        int col = nt + wc * 32 + n * 16 + lr;
#pragma unroll
        for (int j = 0; j < 4; j++)
          UR1[(size_t)(rm + j) * NTOT + col] = f2bf(acc[m][n][j]);
      }
    }
    return;
  }

  int b = blockIdx.x - NGEMM;
  unsigned short* Xs = (unsigned short*)big;
  if (t < 64) {
    int sl = sub_label[knn[b * KK + t]];
    sublabs[b * KK + t] = sl;
    slr[t] = (t == 0) ? (NSUB + b) : sl;
    float s2 = (t == 0) ? 0.f : simm[sl];
    nks[t] = (t == 0) ? norms0[b] : ((s2 > 0.f) ? sqrtf(s2) : 0.f);
    wjs[t] = expf(all_pred[(size_t)(b * KK + t) * 2 + 1]);
  }
  __syncthreads();

  const int rb = w & 3;
  const int cp = w >> 2;
  int rloc[4], clsw[4];
#pragma unroll
  for (int i = 0; i < 4; i++) {
    rloc[i] = w * 8 + i * 2 + (lane >> 5);
    clsw[i] = (lane & 31) ^ (rloc[i] & 7);
  }

  f32x4 acc0 = {0.f, 0.f, 0.f, 0.f}, acc1 = {0.f, 0.f, 0.f, 0.f};
  for (int c = 0; c < 8; c++) {
    if (c) __syncthreads();
#pragma unroll
    for (int i = 0; i < 4; i++) {
      const unsigned short* src =
          u_bf + (size_t)slr[rloc[i]] * DIM + c * 256 + clsw[i] * 8;
      __builtin_amdgcn_global_load_lds(
          (const __attribute__((address_space(1))) void*)src,
          (__attribute__((address_space(3))) void*)(Xs + (w * 8 + i * 2) * 256), 16, 0, 0);
    }
    __syncthreads();
#pragma unroll
    for (int ks = 0; ks < 8; ks++) {
      const int ch = ks * 4 + kg;
      int Ra = rb * 16 + lr;
      bf16x8 fa = *(const bf16x8*)&Xs[Ra * 256 + ((ch ^ (Ra & 7)) << 3)];
      int R0 = (cp * 2) * 16 + lr;
      bf16x8 f0 = *(const bf16x8*)&Xs[R0 * 256 + ((ch ^ (R0 & 7)) << 3)];
      int R1 = (cp * 2 + 1) * 16 + lr;
      bf16x8 f1 = *(const bf16x8*)&Xs[R1 * 256 + ((ch ^ (R1 & 7)) << 3)];
      acc0 = __builtin_amdgcn_mfma_f32_16x16x32_bf16(fa, f0, acc0, 0, 0, 0);
      acc1 = __builtin_amdgcn_mfma_f32_16x16x32_bf16(fa, f1, acc1, 0, 0, 0);
    }
  }

  __syncthreads();
  float* Cs = (float*)big;
#pragma unroll
  for (int r = 0; r < 4; r++) {
    Cs[(rb * 16 + kg * 4 + r) * 68 + cp * 32 + lr] = acc0[r];
    Cs[(rb * 16 + kg * 4 + r) * 68 + cp * 32 + 16 + lr] = acc1[r];
  }
  __syncthreads();

  int row = t >> 3, seg = t & 7;
  float nr = nks[row];
  float v[8];
  float mx = -1e30f;
#pragma unroll
  for (int i = 0; i < 8; i++) {
    int j = seg * 8 + i;
    v[i] = Cs[row * 68 + j] * nr * nks[j] * wjs[j];
    mx = fmaxf(mx, v[i]);
  }
  mx = fmaxf(mx, __shfl_xor(mx, 1));
  mx = fmaxf(mx, __shfl_xor(mx, 2));
  mx = fmaxf(mx, __shfl_xor(mx, 4));
  float sum = 0.f;
#pragma unroll
  for (int i = 0; i < 8; i++) {
    v[i] = expf(v[i] - mx);
    sum += v[i];
  }
  sum += __shfl_xor(sum, 1);
  sum += __shfl_xor(sum, 2);
  sum += __shfl_xor(sum, 4);
  float inv = 1.0f / sum;
  float* outp = A + ((size_t)b * KK + row) * KK + seg * 8;
  *(float4*)(outp)     = make_float4(v[0] * inv, v[1] * inv, v[2] * inv, v[3] * inv);
  *(float4*)(outp + 4) = make_float4(v[4] * inv, v[5] * inv, v[6] * inv, v[7] * inv);
}

// ---- l12c: combine1 + gemm2 + combine2 + classifier, all per-sample --------
__global__ __launch_bounds__(512) void k_l12c(const float* __restrict__ A,
                                              const unsigned short* __restrict__ UR1,
                                              const int* __restrict__ sublabs,
                                              const float* __restrict__ b1,
                                              const unsigned short* __restrict__ W2tp,
                                              const float* __restrict__ b2,
                                              const unsigned short* __restrict__ Wc1t,
                                              const float* __restrict__ bc1,
                                              const float* __restrict__ pa,
                                              const float* __restrict__ Wc2,
                                              const float* __restrict__ bc2,
                                              float* __restrict__ probs) {
  __shared__ char lds[131072];
  unsigned short* x1s = (unsigned short*)lds;              // [64][512] 64KB
  char* R = lds + 65536;
  unsigned short* Pl = (unsigned short*)R;                 // [64][80]
  unsigned short* Bl = (unsigned short*)(R + 10240);       // [128][80]
  unsigned short* Ag = (unsigned short*)(R + 30720);       // [64][136]
  float* Raf = (float*)(R + 48128);                        // [128]
  float* red8 = (float*)(R + 48640);                       // [64][8]
  int* slh = (int*)(R + 50688);                            // [64]
  unsigned short* Ws = (unsigned short*)R;                 // stage A: [512][64] 64KB
  unsigned short* Za = (unsigned short*)lds;               // stage B: [64][264]
  unsigned short* Zb = (unsigned short*)(lds + 34816);     // [256][72]
  unsigned short* Pl2 = (unsigned short*)(lds + 71680);    // [64][72]
  unsigned short* x2s = (unsigned short*)(lds + 34816);    // stage C: [64][256]
  unsigned short* Ws2 = (unsigned short*)lds;              // stage C: [256][64]
  float* Lred = (float*)(lds + 71680);                     // [64][8][2]

  const int b = blockIdx.x;
  const int t = threadIdx.x;
  const int w = t >> 6, lane = t & 63;
  const int lr = lane & 15, kg = lane >> 4;
  constexpr int NSTR = 2 * NHID;

  if (t < 64) slh[t] = sublabs[b * KK + t];
  {
    int pk = t & 63, pp = t >> 6;
    const float* Arow = A + ((size_t)b * KK + pk) * KK;
    float part = 0.f;
#pragma unroll
    for (int e = 0; e < 8; e++) {
      int j = pp * 8 + e;
      float av = Arow[j];
      if (j > 0) {
        Pl[pk * 80 + j] = f2bf(av);
        part += av;
      }
    }
    red8[pk * 8 + pp] = part;
  }
  __syncthreads();
  if (t < 64) {
    float rs = 0.f;
#pragma unroll
    for (int p = 0; p < 8; p++) rs += red8[t * 8 + p];
    Pl[t * 80 + 0] = f2bf(-rs);
  }

  for (int db = 0; db < 4; db++) {
    const int dblk = db * 128;
    __syncthreads();
    {
      int gj = t >> 3, gc0 = t & 7;
      size_t brow = (gj == 0) ? (size_t)(NSUB + b) : (size_t)slh[gj];
      const unsigned short* Bp = UR1 + brow * NSTR + NHID + dblk;
#pragma unroll
      for (int it = 0; it < 2; it++) {
        int c = gc0 + it * 8;
        bf16x8 v = *(const bf16x8*)(Bp + c * 8);
#pragma unroll
        for (int e = 0; e < 8; e++) Bl[(c * 8 + e) * 80 + gj] = v[e];
      }
    }
    {
      int ak = t >> 3, ac0 = t & 7;
      const unsigned short* Ap = UR1 + (size_t)slh[ak] * NSTR + dblk;
#pragma unroll
      for (int it = 0; it < 2; it++) {
        int c = ac0 + it * 8;
        *(bf16x8*)&Ag[ak * 136 + c * 8] = *(const bf16x8*)(Ap + c * 8);
      }
      if (t < 128) Raf[t] = bf2f(UR1[(size_t)(NSUB + b) * NSTR + dblk + t]);
    }
    __syncthreads();

    f32x4 acc[4];
#pragma unroll
    for (int m = 0; m < 4; m++) acc[m] = (f32x4){0.f, 0.f, 0.f, 0.f};
#pragma unroll
    for (int ks = 0; ks < 2; ks++) {
      const int ch = ks * 4 + kg;
      bf16x8 bfr = *(const bf16x8*)&Bl[(w * 16 + lr) * 80 + ch * 8];
#pragma unroll
      for (int m = 0; m < 4; m++) {
        bf16x8 af = *(const bf16x8*)&Pl[(m * 16 + lr) * 80 + ch * 8];
        acc[m] = __builtin_amdgcn_mfma_f32_16x16x32_bf16(af, bfr, acc[m], 0, 0, 0);
      }
    }
#pragma unroll
    for (int m = 0; m < 4; m++) {
      int d = w * 16 + lr;
      float bd = b1[dblk + d];
#pragma unroll
      for (int j = 0; j < 4; j++) {
        int k = m * 16 + kg * 4 + j;
        float v = acc[m][j] + bd;
        if (k > 0) v += bf2f(Ag[k * 136 + d]) - Raf[d];
        int cg = dblk + d;
        int C = cg >> 3;
        x1s[k * 512 + (((C ^ (k & 7)) << 3) | (cg & 7))] = f2bf(fmaxf(v, 0.f));
      }
    }
  }
  __syncthreads();

  const int wr = w >> 2, wc = w & 3;
  f32x4 accA[2][8];
#pragma unroll
  for (int m = 0; m < 2; m++)
#pragma unroll
    for (int n = 0; n < 8; n++) accA[m][n] = (f32x4){0.f, 0.f, 0.f, 0.f};

  for (int kc = 0; kc < 8; kc++) {
    const int k0 = kc * 64;
    if (kc) __syncthreads();
#pragma unroll
    for (int i = 0; i < 8; i++) {
      int r = w * 64 + i * 8 + (lane >> 3);
      int cl = (lane & 7) ^ (r & 7);
      __builtin_amdgcn_global_load_lds(
          (const __attribute__((address_space(1))) void*)(W2tp + (size_t)r * NHID + k0 + cl * 8),
          (__attribute__((address_space(3))) void*)(Ws + (w * 64 + i * 8) * 64), 16, 0, 0);
    }
    __syncthreads();
#pragma unroll
    for (int ks = 0; ks < 2; ks++) {
      const int ch = ks * 4 + kg;
      const int C = kc * 8 + ch;
      bf16x8 af[2], bfr[8];
#pragma unroll
      for (int m = 0; m < 2; m++) {
        int row = wr * 32 + m * 16 + lr;
        af[m] = *(const bf16x8*)&x1s[row * 512 + ((C ^ (row & 7)) << 3)];
      }
#pragma unroll
      for (int n = 0; n < 8; n++) {
        int row = wc * 128 + n * 16 + lr;
        bfr[n] = *(const bf16x8*)&Ws[row * 64 + ((ch ^ (row & 7)) << 3)];
      }
#pragma unroll
      for (int m = 0; m < 2; m++)
#pragma unroll
        for (int n = 0; n < 8; n++)
          accA[m][n] = __builtin_amdgcn_mfma_f32_16x16x32_bf16(af[m], bfr[n], accA[m][n], 0, 0, 0);
    }
  }
  __syncthreads();

#pragma unroll
  for (int m = 0; m < 2; m++) {
#pragma unroll
    for (int n = 0; n < 8; n++) {
      int col = wc * 128 + n * 16 + lr;
#pragma unroll
      for (int j = 0; j < 4; j++) {
        int row = wr * 32 + m * 16 + kg * 4 + j;
        unsigned short hv = f2bf(accA[m][n][j]);
        if (col < 256) Za[row * 264 + col] = hv;
        else           Zb[(col - 256) * 72 + row] = hv;
      }
    }
  }
  {
    const float* Ap = A + (size_t)b * KK * KK + t * 8;
    float4 f0 = *(const float4*)(Ap);
    float4 f1 = *(const float4*)(Ap + 4);
    bf16x8 hv;
    hv[0] = (short)f2bf(f0.x); hv[1] = (short)f2bf(f0.y);
    hv[2] = (short)f2bf(f0.z); hv[3] = (short)f2bf(f0.w);
    hv[4] = (short)f2bf(f1.x); hv[5] = (short)f2bf(f1.y);
    hv[6] = (short)f2bf(f1.z); hv[7] = (short)f2bf(f1.w);
    *(bf16x8*)&Pl2[(t >> 3) * 72 + (t & 7) * 8] = hv;
  }
  __syncthreads();

  f32x4 acc2[4][2];
#pragma unroll
  for (int m = 0; m < 4; m++)
#pragma unroll
    for (int n = 0; n < 2; n++) acc2[m][n] = (f32x4){0.f, 0.f, 0.f, 0.f};
#pragma unroll
  for (int ks = 0; ks < 2; ks++) {
    const int ch = ks * 4 + kg;
    bf16x8 af[4], bfr[2];
#pragma unroll
    for (int m = 0; m < 4; m++) af[m] = *(const bf16x8*)&Pl2[(m * 16 + lr) * 72 + ch * 8];
#pragma unroll
    for (int n = 0; n < 2; n++) bfr[n] = *(const bf16x8*)&Zb[(w * 32 + n * 16 + lr) * 72 + ch * 8];
#pragma unroll
    for (int m = 0; m < 4; m++)
#pragma unroll
      for (int n = 0; n < 2; n++)
        acc2[m][n] = __builtin_amdgcn_mfma_f32_16x16x32_bf16(af[m], bfr[n], acc2[m][n], 0, 0, 0);
  }
  __syncthreads();

#pragma unroll
  for (int m = 0; m < 4; m++) {
#pragma unroll
    for (int n = 0; n < 2; n++) {
      int d = w * 32 + n * 16 + lr;
      float bd = b2[d];
#pragma unroll
      for (int j = 0; j < 4; j++) {
        int k = m * 16 + kg * 4 + j;
        float v = acc2[m][n][j] + bf2f(Za[k * 264 + d]) + bd;
        int C = d >> 3;
        x2s[k * 256 + (((C ^ (k & 7)) << 3) | (d & 7))] = f2bf(fmaxf(v, 0.f));
      }
    }
  }
  __syncthreads();

  f32x4 acc3[4][2];
#pragma unroll
  for (int m = 0; m < 4; m++)
#pragma unroll
    for (int n = 0; n < 2; n++) acc3[m][n] = (f32x4){0.f, 0.f, 0.f, 0.f};

  for (int kc = 0; kc < 4; kc++) {
    const int k0 = kc * 64;
    if (kc) __syncthreads();
#pragma unroll
    for (int i = 0; i < 4; i++) {
      int r = w * 32 + i * 8 + (lane >> 3);
      int cl = (lane & 7) ^ (r & 7);
      __builtin_amdgcn_global_load_lds(
          (const __attribute__((address_space(1))) void*)(Wc1t + (size_t)r * DOUT + k0 + cl * 8),
          (__attribute__((address_space(3))) void*)(Ws2 + (w * 32 + i * 8) * 64), 16, 0, 0);
    }
    __syncthreads();
#pragma unroll
    for (int ks = 0; ks < 2; ks++) {
      const int ch = ks * 4 + kg;
      const int C = kc * 8 + ch;
      bf16x8 af[4], bfr[2];
#pragma unroll
      for (int m = 0; m < 4; m++) {
        int row = m * 16 + lr;
        af[m] = *(const bf16x8*)&x2s[row * 256 + ((C ^ (row & 7)) << 3)];
      }
#pragma unroll
      for (int n = 0; n < 2; n++) {
        int row = w * 32 + n * 16 + lr;
        bfr[n] = *(const bf16x8*)&Ws2[row * 64 + ((ch ^ (row & 7)) << 3)];
      }
#pragma unroll
      for (int m = 0; m < 4; m++)
#pragma unroll
        for (int n = 0; n < 2; n++)
          acc3[m][n] = __builtin_amdgcn_mfma_f32_16x16x32_bf16(af[m], bfr[n], acc3[m][n], 0, 0, 0);
    }
  }

  float bc1v[2], pav[2], w0v[2], w1v[2];
#pragma unroll
  for (int n = 0; n < 2; n++) {
    int col = w * 32 + n * 16 + lr;
    bc1v[n] = bc1[col];
    pav[n] = pa[col];
    w0v[n] = Wc2[col * 2 + 0];
    w1v[n] = Wc2[col * 2 + 1];
  }
  __syncthreads();
#pragma unroll
  for (int m = 0; m < 4; m++) {
#pragma unroll
    for (int j = 0; j < 4; j++) {
      float p0 = 0.f, p1 = 0.f;
#pragma unroll
      for (int n = 0; n < 2; n++) {
        float h = acc3[m][n][j] + bc1v[n];
        h = (h >= 0.f) ? h : pav[n] * h;
        p0 += h * w0v[n];
        p1 += h * w1v[n];
      }
      p0 += __shfl_xor(p0, 1); p1 += __shfl_xor(p1, 1);
      p0 += __shfl_xor(p0, 2); p1 += __shfl_xor(p1, 2);
      p0 += __shfl_xor(p0, 4); p1 += __shfl_xor(p1, 4);
      p0 += __shfl_xor(p0, 8); p1 += __shfl_xor(p1, 8);
      if (lr == 0) {
        int rowl = m * 16 + kg * 4 + j;
        Lred[(rowl * 8 + w) * 2 + 0] = p0;
        Lred[(rowl * 8 + w) * 2 + 1] = p1;
      }
    }
  }
  __syncthreads();
  if (t < 64) {
    float l0 = bc2[0], l1 = bc2[1];
#pragma unroll
    for (int p = 0; p < 8; p++) {
      l0 += Lred[(t * 8 + p) * 2 + 0];
      l1 += Lred[(t * 8 + p) * 2 + 1];
    }
    float m = fmaxf(l0, l1);
    float e0 = expf(l0 - m), e1 = expf(l1 - m);
    float inv = 1.0f / (e0 + e1);
    *(float2*)(probs + (size_t)(b * KK + t) * 2) = make_float2(e0 * inv, e1 * inv);
  }
}

// ---------------------------------------------------------------------------

extern "C" void kernel_launch(void* const* d_in, const int* in_sizes, int n_in,
                              void* d_out, int out_size, void* d_ws, size_t ws_size,
                              hipStream_t stream) {
  const int* indexes = (const int*)d_in[0];
  const float* features = (const float*)d_in[1];
  const int* sub_label = (const int*)d_in[3];
  const int* knn = (const int*)d_in[6];
  const float* all_pred = (const float*)d_in[7];
  const float* W1 = (const float*)d_in[9];
  const float* b1 = (const float*)d_in[10];
  const float* W2 = (const float*)d_in[11];
  const float* b2 = (const float*)d_in[12];
  const float* Wc1 = (const float*)d_in[13];
  const float* bc1 = (const float*)d_in[14];
  const float* pa = (const float*)d_in[15];
  const float* Wc2 = (const float*)d_in[16];
  const float* bc2 = (const float*)d_in[17];

  float* out = (float*)d_out;
  float* probs = out;
  float* simm = out + 32768;
  float* submean = out + 34768;
  float* nums = out + 4130768;

  char* ws = (char*)d_ws;
  size_t off = 0;
  unsigned short* u_bf = (unsigned short*)(ws + off); off += (size_t)MU * DIM * 2;
  unsigned short* UR1  = (unsigned short*)(ws + off); off += (size_t)MU * 2 * NHID * 2;
  unsigned short* W1tp = (unsigned short*)(ws + off); off += (size_t)(2 * NHID) * DIM * 2;
  unsigned short* W2tp = (unsigned short*)(ws + off); off += (size_t)(2 * DOUT) * NHID * 2;
  unsigned short* Wc1t = (unsigned short*)(ws + off); off += (size_t)DOUT * DOUT * 2;
  float* Abuf = (float*)(ws + off); off += (size_t)MM * KK * 4;
  int* cnt     = (int*)(ws + off); off += NSUB * 4;
  int* rowlist = (int*)(ws + off); off += (size_t)NSUB * CAP * 4;
  int* sublabs = (int*)(ws + off); off += (size_t)MM * 4;
  float* norms0 = (float*)(ws + off); off += (size_t)BB * 4;

  (void)hipMemsetAsync(cnt, 0, NSUB * sizeof(int), stream);

  k_build<<<(NROW + 255) / 256, 256, 0, stream>>>(sub_label, cnt, rowlist);
  k_sum_misc<<<NSUB + 2368 + 304, 256, 0, stream>>>(
      features, rowlist, cnt, submean, simm, nums, u_bf,
      W1, W2, Wc1, W1tp, W2tp, Wc1t, indexes, norms0);
  k_gram_gemm<<<NGEMM + BB, 512, 0, stream>>>(u_bf, W1tp, UR1, sub_label, knn,
                                              simm, norms0, all_pred, Abuf, sublabs);
  k_l12c<<<BB, 512, 0, stream>>>(Abuf, UR1, sublabs, b1, W2tp, b2,
                                 Wc1t, bc1, pa, Wc2, bc2, probs);
}

// Round 15
// 179.932 us; speedup vs baseline: 1.0769x; 1.0301x over previous
//
#include <hip/hip_runtime.h>
#include <hip/hip_bf16.h>

// ---------------------------------------------------------------------------
// Sub_Cluster_Level_GCN — round 14: lock in best measured config (= round 9).
//   k_sum_misc: direct rowlist reads (no LDS prefetch — measured regression),
//   4-row unroll, no nontemporal. 4 kernels + 1 memset.
// ---------------------------------------------------------------------------

#define NROW 50000
#define DIM  2048
#define NSUB 2000
#define BB   256
#define KK   64
#define NHID 512
#define DOUT 256
#define MM   (BB * KK)
#define MU   2304
#define CAP  128

typedef __attribute__((ext_vector_type(8))) short bf16x8;
typedef __attribute__((ext_vector_type(4))) float f32x4;

__device__ __forceinline__ unsigned short f2bf(float f) {
  union { float f; unsigned u; } v; v.f = f;
  unsigned r = v.u + 0x7FFF + ((v.u >> 16) & 1);
  return (unsigned short)(r >> 16);
}
__device__ __forceinline__ float bf2f(unsigned short h) {
  union { unsigned u; float f; } v; v.u = ((unsigned)h) << 16;
  return v.f;
}

// ---------------- build: bucketed rowlist ----------------------------------
__global__ __launch_bounds__(256) void k_build(const int* __restrict__ sub_label,
                                               int* __restrict__ cnt,
                                               int* __restrict__ rowlist) {
  int i = blockIdx.x * 256 + threadIdx.x;
  if (i < NROW) {
    int s = sub_label[i];
    int pos = atomicAdd(&cnt[s], 1);
    rowlist[(s << 7) + pos] = i;
  }
}

// --- cluster_sum (2000) + W transposes (2368) + r0 cast (304) in one launch -
__global__ __launch_bounds__(256) void k_sum_misc(const float* __restrict__ features,
                                                  const int* __restrict__ rowlist,
                                                  const int* __restrict__ cnt,
                                                  float* __restrict__ submean,
                                                  float* __restrict__ simm,
                                                  float* __restrict__ nums,
                                                  unsigned short* __restrict__ u_bf,
                                                  const float* __restrict__ W1,
                                                  const float* __restrict__ W2,
                                                  const float* __restrict__ Wc1,
                                                  unsigned short* __restrict__ W1t,
                                                  unsigned short* __restrict__ W2t,
                                                  unsigned short* __restrict__ Wc1t,
                                                  const int* __restrict__ indexes,
                                                  float* __restrict__ norms0) {
  int bid = blockIdx.x;
  int t = threadIdx.x;
  if (bid < NSUB) {
    // ---- cluster mean + simm + nums + u row ----
    int s = bid;
    int n = cnt[s];
    const int* rl = rowlist + (s << 7);
    float acc[8] = {0, 0, 0, 0, 0, 0, 0, 0};
    int r = 0;
    for (; r + 3 < n; r += 4) {
      const float* rA = features + (size_t)rl[r] * DIM + t * 8;
      const float* rB = features + (size_t)rl[r + 1] * DIM + t * 8;
      const float* rC = features + (size_t)rl[r + 2] * DIM + t * 8;
      const float* rD = features + (size_t)rl[r + 3] * DIM + t * 8;
      float4 a0 = *(const float4*)(rA), a1 = *(const float4*)(rA + 4);
      float4 b0 = *(const float4*)(rB), b1 = *(const float4*)(rB + 4);
      float4 c0 = *(const float4*)(rC), c1 = *(const float4*)(rC + 4);
      float4 d0 = *(const float4*)(rD), d1 = *(const float4*)(rD + 4);
      acc[0] += (a0.x + b0.x) + (c0.x + d0.x);
      acc[1] += (a0.y + b0.y) + (c0.y + d0.y);
      acc[2] += (a0.z + b0.z) + (c0.z + d0.z);
      acc[3] += (a0.w + b0.w) + (c0.w + d0.w);
      acc[4] += (a1.x + b1.x) + (c1.x + d1.x);
      acc[5] += (a1.y + b1.y) + (c1.y + d1.y);
      acc[6] += (a1.z + b1.z) + (c1.z + d1.z);
      acc[7] += (a1.w + b1.w) + (c1.w + d1.w);
    }
    for (; r < n; r++) {
      const float* row = features + (size_t)rl[r] * DIM + t * 8;
      float4 v0 = *(const float4*)(row);
      float4 v1 = *(const float4*)(row + 4);
      acc[0] += v0.x; acc[1] += v0.y; acc[2] += v0.z; acc[3] += v0.w;
      acc[4] += v1.x; acc[5] += v1.y; acc[6] += v1.z; acc[7] += v1.w;
    }
    float inv = 1.0f / (float)(n > 0 ? n : 1);
    float m[8];
    float ss = 0.f;
#pragma unroll
    for (int i = 0; i < 8; i++) { m[i] = acc[i] * inv; ss += m[i] * m[i]; }
    float* outp = submean + (size_t)s * DIM + t * 8;
    *(float4*)(outp)     = make_float4(m[0], m[1], m[2], m[3]);
    *(float4*)(outp + 4) = make_float4(m[4], m[5], m[6], m[7]);
    __shared__ float red[256];
    red[t] = ss;
    __syncthreads();
    for (int s2 = 128; s2 > 0; s2 >>= 1) {
      if (t < s2) red[t] += red[t + s2];
      __syncthreads();
    }
    float tot = red[0];
    if (t == 0) {
      simm[s] = tot;
      nums[s] = (float)n;
    }
    float scale = (tot > 0.f) ? (1.0f / sqrtf(tot)) : 0.f;
    bf16x8 o;
    o[0] = (short)f2bf(m[0] * scale); o[1] = (short)f2bf(m[1] * scale);
    o[2] = (short)f2bf(m[2] * scale); o[3] = (short)f2bf(m[3] * scale);
    o[4] = (short)f2bf(m[4] * scale); o[5] = (short)f2bf(m[5] * scale);
    o[6] = (short)f2bf(m[6] * scale); o[7] = (short)f2bf(m[7] * scale);
    *(bf16x8*)(u_bf + (size_t)s * DIM + t * 8) = o;
    return;
  }
  bid -= NSUB;
  if (bid >= 2368) {
    // ---- r0 cast/norm ----
    int row = bid - 2368;
    unsigned short* dst = u_bf + (size_t)(NSUB + row) * DIM + t * 8;
    if (row >= BB) {
      bf16x8 z = {0, 0, 0, 0, 0, 0, 0, 0};
      *(bf16x8*)dst = z;
      return;
    }
    const float* src = features + (size_t)indexes[row] * DIM + t * 8;
    float4 v0 = *(const float4*)(src);
    float4 v1 = *(const float4*)(src + 4);
    float ss = v0.x * v0.x + v0.y * v0.y + v0.z * v0.z + v0.w * v0.w +
               v1.x * v1.x + v1.y * v1.y + v1.z * v1.z + v1.w * v1.w;
    __shared__ float red2[256];
    red2[t] = ss;
    __syncthreads();
    for (int s2 = 128; s2 > 0; s2 >>= 1) {
      if (t < s2) red2[t] += red2[t + s2];
      __syncthreads();
    }
    float nrm = sqrtf(red2[0]);
    if (t == 0) norms0[row] = nrm;
    float scale = 1.0f / nrm;
    bf16x8 o;
    o[0] = (short)f2bf(v0.x * scale); o[1] = (short)f2bf(v0.y * scale);
    o[2] = (short)f2bf(v0.z * scale); o[3] = (short)f2bf(v0.w * scale);
    o[4] = (short)f2bf(v1.x * scale); o[5] = (short)f2bf(v1.y * scale);
    o[6] = (short)f2bf(v1.z * scale); o[7] = (short)f2bf(v1.w * scale);
    *(bf16x8*)dst = o;
    return;
  }
  // ---- W transpose tiles ----
  const float* src;
  unsigned short* dst;
  int Nsrc, Kdst, ntn, local;
  if (bid < 1024)      { local = bid;        src = W1;                        dst = W1t;                      Nsrc = NHID; Kdst = DIM;  ntn = 16; }
  else if (bid < 2048) { local = bid - 1024; src = W1 + (size_t)DIM * NHID;   dst = W1t + (size_t)NHID * DIM; Nsrc = NHID; Kdst = DIM;  ntn = 16; }
  else if (bid < 2176) { local = bid - 2048; src = W2;                        dst = W2t;                      Nsrc = DOUT; Kdst = NHID; ntn = 8; }
  else if (bid < 2304) { local = bid - 2176; src = W2 + (size_t)NHID * DOUT;  dst = W2t + (size_t)DOUT * NHID;Nsrc = DOUT; Kdst = NHID; ntn = 8; }
  else                 { local = bid - 2304; src = Wc1;                       dst = Wc1t;                     Nsrc = DOUT; Kdst = DOUT; ntn = 8; }
  int n0 = (local % ntn) * 32, k0 = (local / ntn) * 32;
  __shared__ float tile[32][33];
  int c = t & 31, r8 = t >> 5;
#pragma unroll
  for (int i = 0; i < 4; i++) {
    int r = r8 + i * 8;
    tile[r][c] = src[(size_t)(k0 + r) * Nsrc + n0 + c];
  }
  __syncthreads();
#pragma unroll
  for (int i = 0; i < 4; i++) {
    int r = r8 + i * 8;
    dst[(size_t)(n0 + r) * Kdst + k0 + c] = f2bf(tile[c][r]);
  }
}

// ------- fused gram (256 blocks) + gemm1 (144 tiles), 512 threads -----------
#define NGEMM 144
__global__ __launch_bounds__(512) void k_gram_gemm(const unsigned short* __restrict__ u_bf,
                                                   const unsigned short* __restrict__ W1tp,
                                                   unsigned short* __restrict__ UR1,
                                                   const int* __restrict__ sub_label,
                                                   const int* __restrict__ knn,
                                                   const float* __restrict__ simm,
                                                   const float* __restrict__ norms0,
                                                   const float* __restrict__ all_pred,
                                                   float* __restrict__ A,
                                                   int* __restrict__ sublabs) {
  __shared__ char big[32768];
  __shared__ int slr[64];
  __shared__ float nks[64], wjs[64];
  const int t = threadIdx.x;
  const int w = t >> 6, lane = t & 63;
  const int lr = lane & 15, kg = lane >> 4;

  if (blockIdx.x < NGEMM) {
    constexpr int KTOT = DIM;
    constexpr int NTOT = 2 * NHID;
    unsigned short* As = (unsigned short*)big;
    unsigned short* Bs = (unsigned short*)(big + 16384);
    int orig = blockIdx.x;
    int swz = (orig & 7) * (NGEMM / 8) + (orig >> 3);
    const int nt = (swz & 7) * 128;
    const int mt = (swz >> 3) * 128;
    const int wr = w >> 2, wc = w & 3;

    f32x4 acc[4][2];
#pragma unroll
    for (int m = 0; m < 4; m++)
#pragma unroll
      for (int n = 0; n < 2; n++) acc[m][n] = (f32x4){0.f, 0.f, 0.f, 0.f};

    for (int kc = 0; kc < KTOT / 64; kc++) {
      const int k0 = kc * 64;
#pragma unroll
      for (int i = 0; i < 2; i++) {
        int q = (w * 2 + i) * 64 + lane;
        int r = q >> 3;
        int cl = (q & 7) ^ (r & 7);
        __builtin_amdgcn_global_load_lds(
            (const __attribute__((address_space(1))) void*)(u_bf + (size_t)(mt + r) * KTOT + k0 + cl * 8),
            (__attribute__((address_space(3))) void*)(As + (w * 2 + i) * 512), 16, 0, 0);
      }
#pragma unroll
      for (int i = 0; i < 2; i++) {
        int q = (w * 2 + i) * 64 + lane;
        int r = q >> 3;
        int cl = (q & 7) ^ (r & 7);
        __builtin_amdgcn_global_load_lds(
            (const __attribute__((address_space(1))) void*)(W1tp + (size_t)(nt + r) * KTOT + k0 + cl * 8),
            (__attribute__((address_space(3))) void*)(Bs + (w * 2 + i) * 512), 16, 0, 0);
      }
      __syncthreads();
#pragma unroll
      for (int ks = 0; ks < 2; ks++) {
        bf16x8 af[4], bfr[2];
        const int ch = ks * 4 + kg;
#pragma unroll
        for (int m = 0; m < 4; m++) {
          int row = wr * 64 + m * 16 + lr;
          af[m] = *(const bf16x8*)&As[row * 64 + ((ch ^ (row & 7)) << 3)];
        }
#pragma unroll
        for (int n = 0; n < 2; n++) {
          int row = wc * 32 + n * 16 + lr;
          bfr[n] = *(const bf16x8*)&Bs[row * 64 + ((ch ^ (row & 7)) << 3)];
        }
#pragma unroll
        for (int m = 0; m < 4; m++)
#pragma unroll
          for (int n = 0; n < 2; n++)
            acc[m][n] = __builtin_amdgcn_mfma_f32_16x16x32_bf16(af[m], bfr[n], acc[m][n], 0, 0, 0);
      }
      __syncthreads();
    }
#pragma unroll
    for (int m = 0; m < 4; m++) {
      int rm = mt + wr * 64 + m * 16 + kg * 4;
#pragma unroll
      for (int n = 0; n < 2; n++) {
        int col = nt + wc * 32 + n * 16 + lr;
#pragma unroll
        for (int j = 0; j < 4; j++)
          UR1[(size_t)(rm + j) * NTOT + col] = f2bf(acc[m][n][j]);
      }
    }
    return;
  }

  int b = blockIdx.x - NGEMM;
  unsigned short* Xs = (unsigned short*)big;
  if (t < 64) {
    int sl = sub_label[knn[b * KK + t]];
    sublabs[b * KK + t] = sl;
    slr[t] = (t == 0) ? (NSUB + b) : sl;
    float s2 = (t == 0) ? 0.f : simm[sl];
    nks[t] = (t == 0) ? norms0[b] : ((s2 > 0.f) ? sqrtf(s2) : 0.f);
    wjs[t] = expf(all_pred[(size_t)(b * KK + t) * 2 + 1]);
  }
  __syncthreads();

  const int rb = w & 3;
  const int cp = w >> 2;
  int rloc[4], clsw[4];
#pragma unroll
  for (int i = 0; i < 4; i++) {
    rloc[i] = w * 8 + i * 2 + (lane >> 5);
    clsw[i] = (lane & 31) ^ (rloc[i] & 7);
  }

  f32x4 acc0 = {0.f, 0.f, 0.f, 0.f}, acc1 = {0.f, 0.f, 0.f, 0.f};
  for (int c = 0; c < 8; c++) {
    if (c) __syncthreads();
#pragma unroll
    for (int i = 0; i < 4; i++) {
      const unsigned short* src =
          u_bf + (size_t)slr[rloc[i]] * DIM + c * 256 + clsw[i] * 8;
      __builtin_amdgcn_global_load_lds(
          (const __attribute__((address_space(1))) void*)src,
          (__attribute__((address_space(3))) void*)(Xs + (w * 8 + i * 2) * 256), 16, 0, 0);
    }
    __syncthreads();
#pragma unroll
    for (int ks = 0; ks < 8; ks++) {
      const int ch = ks * 4 + kg;
      int Ra = rb * 16 + lr;
      bf16x8 fa = *(const bf16x8*)&Xs[Ra * 256 + ((ch ^ (Ra & 7)) << 3)];
      int R0 = (cp * 2) * 16 + lr;
      bf16x8 f0 = *(const bf16x8*)&Xs[R0 * 256 + ((ch ^ (R0 & 7)) << 3)];
      int R1 = (cp * 2 + 1) * 16 + lr;
      bf16x8 f1 = *(const bf16x8*)&Xs[R1 * 256 + ((ch ^ (R1 & 7)) << 3)];
      acc0 = __builtin_amdgcn_mfma_f32_16x16x32_bf16(fa, f0, acc0, 0, 0, 0);
      acc1 = __builtin_amdgcn_mfma_f32_16x16x32_bf16(fa, f1, acc1, 0, 0, 0);
    }
  }

  __syncthreads();
  float* Cs = (float*)big;
#pragma unroll
  for (int r = 0; r < 4; r++) {
    Cs[(rb * 16 + kg * 4 + r) * 68 + cp * 32 + lr] = acc0[r];
    Cs[(rb * 16 + kg * 4 + r) * 68 + cp * 32 + 16 + lr] = acc1[r];
  }
  __syncthreads();

  int row = t >> 3, seg = t & 7;
  float nr = nks[row];
  float v[8];
  float mx = -1e30f;
#pragma unroll
  for (int i = 0; i < 8; i++) {
    int j = seg * 8 + i;
    v[i] = Cs[row * 68 + j] * nr * nks[j] * wjs[j];
    mx = fmaxf(mx, v[i]);
  }
  mx = fmaxf(mx, __shfl_xor(mx, 1));
  mx = fmaxf(mx, __shfl_xor(mx, 2));
  mx = fmaxf(mx, __shfl_xor(mx, 4));
  float sum = 0.f;
#pragma unroll
  for (int i = 0; i < 8; i++) {
    v[i] = expf(v[i] - mx);
    sum += v[i];
  }
  sum += __shfl_xor(sum, 1);
  sum += __shfl_xor(sum, 2);
  sum += __shfl_xor(sum, 4);
  float inv = 1.0f / sum;
  float* outp = A + ((size_t)b * KK + row) * KK + seg * 8;
  *(float4*)(outp)     = make_float4(v[0] * inv, v[1] * inv, v[2] * inv, v[3] * inv);
  *(float4*)(outp + 4) = make_float4(v[4] * inv, v[5] * inv, v[6] * inv, v[7] * inv);
}

// ---- l12c: combine1 + gemm2 + combine2 + classifier, all per-sample --------
__global__ __launch_bounds__(512) void k_l12c(const float* __restrict__ A,
                                              const unsigned short* __restrict__ UR1,
                                              const int* __restrict__ sublabs,
                                              const float* __restrict__ b1,
                                              const unsigned short* __restrict__ W2tp,
                                              const float* __restrict__ b2,
                                              const unsigned short* __restrict__ Wc1t,
                                              const float* __restrict__ bc1,
                                              const float* __restrict__ pa,
                                              const float* __restrict__ Wc2,
                                              const float* __restrict__ bc2,
                                              float* __restrict__ probs) {
  __shared__ char lds[131072];
  unsigned short* x1s = (unsigned short*)lds;              // [64][512] 64KB
  char* R = lds + 65536;
  unsigned short* Pl = (unsigned short*)R;                 // [64][80]
  unsigned short* Bl = (unsigned short*)(R + 10240);       // [128][80]
  unsigned short* Ag = (unsigned short*)(R + 30720);       // [64][136]
  float* Raf = (float*)(R + 48128);                        // [128]
  float* red8 = (float*)(R + 48640);                       // [64][8]
  int* slh = (int*)(R + 50688);                            // [64]
  unsigned short* Ws = (unsigned short*)R;                 // stage A: [512][64] 64KB
  unsigned short* Za = (unsigned short*)lds;               // stage B: [64][264]
  unsigned short* Zb = (unsigned short*)(lds + 34816);     // [256][72]
  unsigned short* Pl2 = (unsigned short*)(lds + 71680);    // [64][72]
  unsigned short* x2s = (unsigned short*)(lds + 34816);    // stage C: [64][256]
  unsigned short* Ws2 = (unsigned short*)lds;              // stage C: [256][64]
  float* Lred = (float*)(lds + 71680);                     // [64][8][2]

  const int b = blockIdx.x;
  const int t = threadIdx.x;
  const int w = t >> 6, lane = t & 63;
  const int lr = lane & 15, kg = lane >> 4;
  constexpr int NSTR = 2 * NHID;

  if (t < 64) slh[t] = sublabs[b * KK + t];
  {
    int pk = t & 63, pp = t >> 6;
    const float* Arow = A + ((size_t)b * KK + pk) * KK;
    float part = 0.f;
#pragma unroll
    for (int e = 0; e < 8; e++) {
      int j = pp * 8 + e;
      float av = Arow[j];
      if (j > 0) {
        Pl[pk * 80 + j] = f2bf(av);
        part += av;
      }
    }
    red8[pk * 8 + pp] = part;
  }
  __syncthreads();
  if (t < 64) {
    float rs = 0.f;
#pragma unroll
    for (int p = 0; p < 8; p++) rs += red8[t * 8 + p];
    Pl[t * 80 + 0] = f2bf(-rs);
  }

  for (int db = 0; db < 4; db++) {
    const int dblk = db * 128;
    __syncthreads();
    {
      int gj = t >> 3, gc0 = t & 7;
      size_t brow = (gj == 0) ? (size_t)(NSUB + b) : (size_t)slh[gj];
      const unsigned short* Bp = UR1 + brow * NSTR + NHID + dblk;
#pragma unroll
      for (int it = 0; it < 2; it++) {
        int c = gc0 + it * 8;
        bf16x8 v = *(const bf16x8*)(Bp + c * 8);
#pragma unroll
        for (int e = 0; e < 8; e++) Bl[(c * 8 + e) * 80 + gj] = v[e];
      }
    }
    {
      int ak = t >> 3, ac0 = t & 7;
      const unsigned short* Ap = UR1 + (size_t)slh[ak] * NSTR + dblk;
#pragma unroll
      for (int it = 0; it < 2; it++) {
        int c = ac0 + it * 8;
        *(bf16x8*)&Ag[ak * 136 + c * 8] = *(const bf16x8*)(Ap + c * 8);
      }
      if (t < 128) Raf[t] = bf2f(UR1[(size_t)(NSUB + b) * NSTR + dblk + t]);
    }
    __syncthreads();

    f32x4 acc[4];
#pragma unroll
    for (int m = 0; m < 4; m++) acc[m] = (f32x4){0.f, 0.f, 0.f, 0.f};
#pragma unroll
    for (int ks = 0; ks < 2; ks++) {
      const int ch = ks * 4 + kg;
      bf16x8 bfr = *(const bf16x8*)&Bl[(w * 16 + lr) * 80 + ch * 8];
#pragma unroll
      for (int m = 0; m < 4; m++) {
        bf16x8 af = *(const bf16x8*)&Pl[(m * 16 + lr) * 80 + ch * 8];
        acc[m] = __builtin_amdgcn_mfma_f32_16x16x32_bf16(af, bfr, acc[m], 0, 0, 0);
      }
    }
#pragma unroll
    for (int m = 0; m < 4; m++) {
      int d = w * 16 + lr;
      float bd = b1[dblk + d];
#pragma unroll
      for (int j = 0; j < 4; j++) {
        int k = m * 16 + kg * 4 + j;
        float v = acc[m][j] + bd;
        if (k > 0) v += bf2f(Ag[k * 136 + d]) - Raf[d];
        int cg = dblk + d;
        int C = cg >> 3;
        x1s[k * 512 + (((C ^ (k & 7)) << 3) | (cg & 7))] = f2bf(fmaxf(v, 0.f));
      }
    }
  }
  __syncthreads();

  const int wr = w >> 2, wc = w & 3;
  f32x4 accA[2][8];
#pragma unroll
  for (int m = 0; m < 2; m++)
#pragma unroll
    for (int n = 0; n < 8; n++) accA[m][n] = (f32x4){0.f, 0.f, 0.f, 0.f};

  for (int kc = 0; kc < 8; kc++) {
    const int k0 = kc * 64;
    if (kc) __syncthreads();
#pragma unroll
    for (int i = 0; i < 8; i++) {
      int r = w * 64 + i * 8 + (lane >> 3);
      int cl = (lane & 7) ^ (r & 7);
      __builtin_amdgcn_global_load_lds(
          (const __attribute__((address_space(1))) void*)(W2tp + (size_t)r * NHID + k0 + cl * 8),
          (__attribute__((address_space(3))) void*)(Ws + (w * 64 + i * 8) * 64), 16, 0, 0);
    }
    __syncthreads();
#pragma unroll
    for (int ks = 0; ks < 2; ks++) {
      const int ch = ks * 4 + kg;
      const int C = kc * 8 + ch;
      bf16x8 af[2], bfr[8];
#pragma unroll
      for (int m = 0; m < 2; m++) {
        int row = wr * 32 + m * 16 + lr;
        af[m] = *(const bf16x8*)&x1s[row * 512 + ((C ^ (row & 7)) << 3)];
      }
#pragma unroll
      for (int n = 0; n < 8; n++) {
        int row = wc * 128 + n * 16 + lr;
        bfr[n] = *(const bf16x8*)&Ws[row * 64 + ((ch ^ (row & 7)) << 3)];
      }
#pragma unroll
      for (int m = 0; m < 2; m++)
#pragma unroll
        for (int n = 0; n < 8; n++)
          accA[m][n] = __builtin_amdgcn_mfma_f32_16x16x32_bf16(af[m], bfr[n], accA[m][n], 0, 0, 0);
    }
  }
  __syncthreads();

#pragma unroll
  for (int m = 0; m < 2; m++) {
#pragma unroll
    for (int n = 0; n < 8; n++) {
      int col = wc * 128 + n * 16 + lr;
#pragma unroll
      for (int j = 0; j < 4; j++) {
        int row = wr * 32 + m * 16 + kg * 4 + j;
        unsigned short hv = f2bf(accA[m][n][j]);
        if (col < 256) Za[row * 264 + col] = hv;
        else           Zb[(col - 256) * 72 + row] = hv;
      }
    }
  }
  {
    const float* Ap = A + (size_t)b * KK * KK + t * 8;
    float4 f0 = *(const float4*)(Ap);
    float4 f1 = *(const float4*)(Ap + 4);
    bf16x8 hv;
    hv[0] = (short)f2bf(f0.x); hv[1] = (short)f2bf(f0.y);
    hv[2] = (short)f2bf(f0.z); hv[3] = (short)f2bf(f0.w);
    hv[4] = (short)f2bf(f1.x); hv[5] = (short)f2bf(f1.y);
    hv[6] = (short)f2bf(f1.z); hv[7] = (short)f2bf(f1.w);
    *(bf16x8*)&Pl2[(t >> 3) * 72 + (t & 7) * 8] = hv;
  }
  __syncthreads();

  f32x4 acc2[4][2];
#pragma unroll
  for (int m = 0; m < 4; m++)
#pragma unroll
    for (int n = 0; n < 2; n++) acc2[m][n] = (f32x4){0.f, 0.f, 0.f, 0.f};
#pragma unroll
  for (int ks = 0; ks < 2; ks++) {
    const int ch = ks * 4 + kg;
    bf16x8 af[4], bfr[2];
#pragma unroll
    for (int m = 0; m < 4; m++) af[m] = *(const bf16x8*)&Pl2[(m * 16 + lr) * 72 + ch * 8];
#pragma unroll
    for (int n = 0; n < 2; n++) bfr[n] = *(const bf16x8*)&Zb[(w * 32 + n * 16 + lr) * 72 + ch * 8];
#pragma unroll
    for (int m = 0; m < 4; m++)
#pragma unroll
      for (int n = 0; n < 2; n++)
        acc2[m][n] = __builtin_amdgcn_mfma_f32_16x16x32_bf16(af[m], bfr[n], acc2[m][n], 0, 0, 0);
  }
  __syncthreads();

#pragma unroll
  for (int m = 0; m < 4; m++) {
#pragma unroll
    for (int n = 0; n < 2; n++) {
      int d = w * 32 + n * 16 + lr;
      float bd = b2[d];
#pragma unroll
      for (int j = 0; j < 4; j++) {
        int k = m * 16 + kg * 4 + j;
        float v = acc2[m][n][j] + bf2f(Za[k * 264 + d]) + bd;
        int C = d >> 3;
        x2s[k * 256 + (((C ^ (k & 7)) << 3) | (d & 7))] = f2bf(fmaxf(v, 0.f));
      }
    }
  }
  __syncthreads();

  f32x4 acc3[4][2];
#pragma unroll
  for (int m = 0; m < 4; m++)
#pragma unroll
    for (int n = 0; n < 2; n++) acc3[m][n] = (f32x4){0.f, 0.f, 0.f, 0.f};

  for (int kc = 0; kc < 4; kc++) {
    const int k0 = kc * 64;
    if (kc) __syncthreads();
#pragma unroll
    for (int i = 0; i < 4; i++) {
      int r = w * 32 + i * 8 + (lane >> 3);
      int cl = (lane & 7) ^ (r & 7);
      __builtin_amdgcn_global_load_lds(
          (const __attribute__((address_space(1))) void*)(Wc1t + (size_t)r * DOUT + k0 + cl * 8),
          (__attribute__((address_space(3))) void*)(Ws2 + (w * 32 + i * 8) * 64), 16, 0, 0);
    }
    __syncthreads();
#pragma unroll
    for (int ks = 0; ks < 2; ks++) {
      const int ch = ks * 4 + kg;
      const int C = kc * 8 + ch;
      bf16x8 af[4], bfr[2];
#pragma unroll
      for (int m = 0; m < 4; m++) {
        int row = m * 16 + lr;
        af[m] = *(const bf16x8*)&x2s[row * 256 + ((C ^ (row & 7)) << 3)];
      }
#pragma unroll
      for (int n = 0; n < 2; n++) {
        int row = w * 32 + n * 16 + lr;
        bfr[n] = *(const bf16x8*)&Ws2[row * 64 + ((ch ^ (row & 7)) << 3)];
      }
#pragma unroll
      for (int m = 0; m < 4; m++)
#pragma unroll
        for (int n = 0; n < 2; n++)
          acc3[m][n] = __builtin_amdgcn_mfma_f32_16x16x32_bf16(af[m], bfr[n], acc3[m][n], 0, 0, 0);
    }
  }

  float bc1v[2], pav[2], w0v[2], w1v[2];
#pragma unroll
  for (int n = 0; n < 2; n++) {
    int col = w * 32 + n * 16 + lr;
    bc1v[n] = bc1[col];
    pav[n] = pa[col];
    w0v[n] = Wc2[col * 2 + 0];
    w1v[n] = Wc2[col * 2 + 1];
  }
  __syncthreads();
#pragma unroll
  for (int m = 0; m < 4; m++) {
#pragma unroll
    for (int j = 0; j < 4; j++) {
      float p0 = 0.f, p1 = 0.f;
#pragma unroll
      for (int n = 0; n < 2; n++) {
        float h = acc3[m][n][j] + bc1v[n];
        h = (h >= 0.f) ? h : pav[n] * h;
        p0 += h * w0v[n];
        p1 += h * w1v[n];
      }
      p0 += __shfl_xor(p0, 1); p1 += __shfl_xor(p1, 1);
      p0 += __shfl_xor(p0, 2); p1 += __shfl_xor(p1, 2);
      p0 += __shfl_xor(p0, 4); p1 += __shfl_xor(p1, 4);
      p0 += __shfl_xor(p0, 8); p1 += __shfl_xor(p1, 8);
      if (lr == 0) {
        int rowl = m * 16 + kg * 4 + j;
        Lred[(rowl * 8 + w) * 2 + 0] = p0;
        Lred[(rowl * 8 + w) * 2 + 1] = p1;
      }
    }
  }
  __syncthreads();
  if (t < 64) {
    float l0 = bc2[0], l1 = bc2[1];
#pragma unroll
    for (int p = 0; p < 8; p++) {
      l0 += Lred[(t * 8 + p) * 2 + 0];
      l1 += Lred[(t * 8 + p) * 2 + 1];
    }
    float m = fmaxf(l0, l1);
    float e0 = expf(l0 - m), e1 = expf(l1 - m);
    float inv = 1.0f / (e0 + e1);
    *(float2*)(probs + (size_t)(b * KK + t) * 2) = make_float2(e0 * inv, e1 * inv);
  }
}

// ---------------------------------------------------------------------------

extern "C" void kernel_launch(void* const* d_in, const int* in_sizes, int n_in,
                              void* d_out, int out_size, void* d_ws, size_t ws_size,
                              hipStream_t stream) {
  const int* indexes = (const int*)d_in[0];
  const float* features = (const float*)d_in[1];
  const int* sub_label = (const int*)d_in[3];
  const int* knn = (const int*)d_in[6];
  const float* all_pred = (const float*)d_in[7];
  const float* W1 = (const float*)d_in[9];
  const float* b1 = (const float*)d_in[10];
  const float* W2 = (const float*)d_in[11];
  const float* b2 = (const float*)d_in[12];
  const float* Wc1 = (const float*)d_in[13];
  const float* bc1 = (const float*)d_in[14];
  const float* pa = (const float*)d_in[15];
  const float* Wc2 = (const float*)d_in[16];
  const float* bc2 = (const float*)d_in[17];

  float* out = (float*)d_out;
  float* probs = out;
  float* simm = out + 32768;
  float* submean = out + 34768;
  float* nums = out + 4130768;

  char* ws = (char*)d_ws;
  size_t off = 0;
  unsigned short* u_bf = (unsigned short*)(ws + off); off += (size_t)MU * DIM * 2;
  unsigned short* UR1  = (unsigned short*)(ws + off); off += (size_t)MU * 2 * NHID * 2;
  unsigned short* W1tp = (unsigned short*)(ws + off); off += (size_t)(2 * NHID) * DIM * 2;
  unsigned short* W2tp = (unsigned short*)(ws + off); off += (size_t)(2 * DOUT) * NHID * 2;
  unsigned short* Wc1t = (unsigned short*)(ws + off); off += (size_t)DOUT * DOUT * 2;
  float* Abuf = (float*)(ws + off); off += (size_t)MM * KK * 4;
  int* cnt     = (int*)(ws + off); off += NSUB * 4;
  int* rowlist = (int*)(ws + off); off += (size_t)NSUB * CAP * 4;
  int* sublabs = (int*)(ws + off); off += (size_t)MM * 4;
  float* norms0 = (float*)(ws + off); off += (size_t)BB * 4;

  (void)hipMemsetAsync(cnt, 0, NSUB * sizeof(int), stream);

  k_build<<<(NROW + 255) / 256, 256, 0, stream>>>(sub_label, cnt, rowlist);
  k_sum_misc<<<NSUB + 2368 + 304, 256, 0, stream>>>(
      features, rowlist, cnt, submean, simm, nums, u_bf,
      W1, W2, Wc1, W1tp, W2tp, Wc1t, indexes, norms0);
  k_gram_gemm<<<NGEMM + BB, 512, 0, stream>>>(u_bf, W1tp, UR1, sub_label, knn,
                                              simm, norms0, all_pred, Abuf, sublabs);
  k_l12c<<<BB, 512, 0, stream>>>(Abuf, UR1, sublabs, b1, W2tp, b2,
                                 Wc1t, bc1, pa, Wc2, bc2, probs);
}